// Round 4
// baseline (579.688 us; speedup 1.0000x reference)
//
#include <hip/hip_runtime.h>

#define N_NODES 100000
#define N_HE    30000
#define N_INC   300000
#define MPAD    100096          // 782 * 128

typedef short  short8  __attribute__((ext_vector_type(8)));
typedef float  floatx4 __attribute__((ext_vector_type(4)));

__device__ inline unsigned short f2bf(float f) {
  unsigned int u = __float_as_uint(f);
  u = (u + 0x7fff + ((u >> 16) & 1)) >> 16;   // round-to-nearest-even
  return (unsigned short)u;
}
__device__ inline unsigned int pack2(float lo, float hi) {
  return (unsigned int)f2bf(lo) | ((unsigned int)f2bf(hi) << 16);
}
__device__ inline void acc8(uint4 rv, float* a) {
  unsigned int u;
  u = rv.x; a[0] += __uint_as_float(u << 16); a[1] += __uint_as_float(u & 0xffff0000u);
  u = rv.y; a[2] += __uint_as_float(u << 16); a[3] += __uint_as_float(u & 0xffff0000u);
  u = rv.z; a[4] += __uint_as_float(u << 16); a[5] += __uint_as_float(u & 0xffff0000u);
  u = rv.w; a[6] += __uint_as_float(u << 16); a[7] += __uint_as_float(u & 0xffff0000u);
}

// ---------------------------------------------------------------- CSR build

__global__ void zero_kernel(int* __restrict__ p, int n) {
  int i = blockIdx.x * blockDim.x + threadIdx.x;
  if (i < n) p[i] = 0;
}

__global__ void count_kernel(const int* __restrict__ nidx, const int* __restrict__ hidx,
                             int* __restrict__ node_cnt, int* __restrict__ he_cnt) {
  int i = blockIdx.x * blockDim.x + threadIdx.x;
  if (i < N_INC) {
    atomicAdd(&node_cnt[nidx[i]], 1);
    atomicAdd(&he_cnt[hidx[i]], 1);
  }
}

__global__ void scan1(const int* __restrict__ cnt, int* __restrict__ incl,
                      int* __restrict__ bsums, int n) {
  __shared__ int tmp[1024];
  int tid = threadIdx.x;
  int i = blockIdx.x * 1024 + tid;
  tmp[tid] = (i < n) ? cnt[i] : 0;
  __syncthreads();
  for (int off = 1; off < 1024; off <<= 1) {
    int t = (tid >= off) ? tmp[tid - off] : 0;
    __syncthreads();
    tmp[tid] += t;
    __syncthreads();
  }
  if (i < n) incl[i] = tmp[tid];
  if (tid == 1023) bsums[blockIdx.x] = tmp[1023];
}

__global__ void scan2(int* __restrict__ bsums, int nb) {
  if (threadIdx.x == 0 && blockIdx.x == 0) {
    int run = 0;
    for (int b = 0; b < nb; b++) { int v = bsums[b]; bsums[b] = run; run += v; }
  }
}

__global__ void scan3(const int* __restrict__ cnt, const int* __restrict__ incl,
                      const int* __restrict__ bsums, int* __restrict__ ptr,
                      int* __restrict__ fill, int n) {
  int i = blockIdx.x * 1024 + threadIdx.x;
  if (i < n) {
    int e = incl[i] - cnt[i] + bsums[blockIdx.x];
    ptr[i] = e;
    fill[i] = e;
    if (i == n - 1) ptr[n] = incl[i] + bsums[blockIdx.x];
  }
}

__global__ void fill_kernel(const int* __restrict__ nidx, const int* __restrict__ hidx,
                            int* __restrict__ node_fill, int* __restrict__ he_fill,
                            int* __restrict__ node_hes, int* __restrict__ he_nodes) {
  int i = blockIdx.x * blockDim.x + threadIdx.x;
  if (i < N_INC) {
    int nn = nidx[i], hh = hidx[i];
    int p1 = atomicAdd(&node_fill[nn], 1);
    node_hes[p1] = hh;
    int p2 = atomicAdd(&he_fill[hh], 1);
    he_nodes[p2] = nn;
  }
}

// ---------------------------------------------------------------- converters / weight fold

// x f32 [N_NODES,128] -> bf16 (pad rows never consumed)
__global__ void convert_x(const float* __restrict__ x, unsigned short* __restrict__ xb) {
  int i = blockIdx.x * 256 + threadIdx.x;      // 8 elems per thread
  if (i >= N_NODES * 16) return;
  const float4* p = (const float4*)x + (size_t)i * 2;
  float4 a = p[0], b = p[1];
  uint4 o;
  o.x = pack2(a.x, a.y); o.y = pack2(a.z, a.w);
  o.z = pack2(b.x, b.y); o.w = pack2(b.z, b.w);
  *(uint4*)(xb + (size_t)i * 8) = o;
}

// WT[n][k] = bf16(W[k][n]*scale[k]);  cvec[n] += partial sum_k shift[k]*W[k][n]
// grid (K/16, ceil(N/256)), block 256. cvec must be pre-zeroed.
__global__ __launch_bounds__(256) void fold_w(
    const float* __restrict__ W, const float* __restrict__ scale,
    const float* __restrict__ shift, unsigned short* __restrict__ WT,
    float* __restrict__ cvec, int K, int N) {
  int n = blockIdx.y * 256 + threadIdx.x;
  if (n >= N) return;
  int k0 = blockIdx.x * 16;
  float c = 0.f;
  unsigned short loc[16];
#pragma unroll
  for (int i = 0; i < 16; i++) {
    int k = k0 + i;
    float w = W[(size_t)k * N + n];
    float s = scale ? scale[k] : 1.f;
    float t = shift ? shift[k] : 0.f;
    loc[i] = f2bf(w * s);
    c += t * w;
  }
  *(uint4*)(WT + (size_t)n * K + k0)     = *(const uint4*)&loc[0];
  *(uint4*)(WT + (size_t)n * K + k0 + 8) = *(const uint4*)&loc[8];
  atomicAdd(cvec + n, c);
}

__global__ void bn_finalize(const float* __restrict__ gsum, const float* __restrict__ gss,
                            const float* __restrict__ g, const float* __restrict__ be,
                            float* __restrict__ scale, float* __restrict__ shift, float invN) {
  int c = threadIdx.x;  // 256
  float m = gsum[c] * invN;
  float v = gss[c] * invN - m * m;
  float sc = g[c] * rsqrtf(v + 1e-5f);
  scale[c] = sc;
  shift[c] = be[c] - m * sc;
}

// ---------------------------------------------------------------- bf16 MFMA GEMM (m97 pattern)
// C[M,N] = A[M,K] @ BT[N,K]^T, all bf16, fp32 accumulate. 128x128 tile, BK=32.

__global__ __launch_bounds__(256) void gemm_mfma(
    const unsigned short* __restrict__ A, const unsigned short* __restrict__ BT,
    unsigned short* __restrict__ C, int K, int N) {
  __shared__ unsigned short As[128 * 32];
  __shared__ unsigned short Bs[128 * 32];
  const int tid  = threadIdx.x;
  const int w    = tid >> 6, lane = tid & 63;
  const int wm   = w & 1,  wn   = w >> 1;
  const int bm   = blockIdx.x * 128, bn = blockIdx.y * 128;
  const int quad = lane >> 4, r16 = lane & 15;

  floatx4 acc[4][4] = {};

  const int srow = (lane >> 2);          // 0..15 within 16-row chunk
  const int scol = (lane & 3) * 8;       // bf16 elems, 16B granules

  for (int kb = 0; kb < K; kb += 32) {
#pragma unroll
    for (int i = 0; i < 2; i++) {
      const int row = (w * 2 + i) * 16 + srow;
      const unsigned short* ga = A  + (size_t)(bm + row) * K + kb + scol;
      const unsigned short* gb = BT + (size_t)(bn + row) * K + kb + scol;
      __builtin_amdgcn_global_load_lds(
          (const __attribute__((address_space(1))) void*)ga,
          (__attribute__((address_space(3))) void*)(&As[(w * 2 + i) * 512]), 16, 0, 0);
      __builtin_amdgcn_global_load_lds(
          (const __attribute__((address_space(1))) void*)gb,
          (__attribute__((address_space(3))) void*)(&Bs[(w * 2 + i) * 512]), 16, 0, 0);
    }
    __syncthreads();
    short8 af[4], bfr[4];
#pragma unroll
    for (int t = 0; t < 4; t++) {
      af[t]  = *(const short8*)&As[(wm * 64 + t * 16 + r16) * 32 + quad * 8];
      bfr[t] = *(const short8*)&Bs[(wn * 64 + t * 16 + r16) * 32 + quad * 8];
    }
#pragma unroll
    for (int mi = 0; mi < 4; mi++)
#pragma unroll
      for (int ni = 0; ni < 4; ni++)
        acc[mi][ni] = __builtin_amdgcn_mfma_f32_16x16x32_bf16(af[mi], bfr[ni], acc[mi][ni], 0, 0, 0);
    __syncthreads();
  }
  // C/D layout: col = lane&15, row = quad*4 + reg
#pragma unroll
  for (int mi = 0; mi < 4; mi++)
#pragma unroll
    for (int ni = 0; ni < 4; ni++)
#pragma unroll
      for (int rr = 0; rr < 4; rr++) {
        int gm = bm + wm * 64 + mi * 16 + quad * 4 + rr;
        int gn = bn + wn * 64 + ni * 16 + r16;
        C[(size_t)gm * N + gn] = f2bf(acc[mi][ni][rr]);
      }
}

// ---------------------------------------------------------------- aggregations (bf16 in/out)

__global__ __launch_bounds__(256) void agg_he(
    const unsigned short* __restrict__ src, const int* __restrict__ ptr,
    const int* __restrict__ idx, unsigned short* __restrict__ dst,
    int F, int shift, int nSeg) {
  int seg = blockIdx.x * (256 >> shift) + (threadIdx.x >> shift);
  if (seg >= nSeg) return;
  int l = threadIdx.x & ((1 << shift) - 1);
  int c0 = l * 8;
  int beg = ptr[seg], end = ptr[seg + 1];
  float a[8] = {};
  for (int j = beg; j < end; j++) {
    int s = idx[j];
    uint4 rv = *(const uint4*)(src + (size_t)s * F + c0);
    acc8(rv, a);
  }
  float inv = (end > beg) ? 1.0f / (float)(end - beg) : 0.0f;
  uint4 o;
  o.x = pack2(a[0] * inv, a[1] * inv);
  o.y = pack2(a[2] * inv, a[3] * inv);
  o.z = pack2(a[4] * inv, a[5] * inv);
  o.w = pack2(a[6] * inv, a[7] * inv);
  *(uint4*)(dst + (size_t)seg * F + c0) = o;
}

// hyperedge->node, F=256, fused bias(+cvec if deg>0) + relu + BN stats. bf16 out.
// 32 nodes per block (8 groups of 32 lanes x 4 nodes each) -> grid 3125, high occupancy.
__global__ __launch_bounds__(256) void node_agg_bn(
    const unsigned short* __restrict__ he, const int* __restrict__ nptr,
    const int* __restrict__ nhes, const float* __restrict__ b,
    const float* __restrict__ cvec, unsigned short* __restrict__ dst,
    float* __restrict__ gsum, float* __restrict__ gss) {
  const int F = 256;
  const int half = threadIdx.x >> 5, l = threadIdx.x & 31, c0 = l * 8;
  float bb[8], cc[8];
#pragma unroll
  for (int j = 0; j < 8; j++) { bb[j] = b[c0 + j]; cc[j] = cvec[c0 + j]; }
  float s[8] = {}, ss[8] = {};
#pragma unroll
  for (int i = 0; i < 4; i++) {
    int n = blockIdx.x * 32 + i * 8 + half;
    if (n >= N_NODES) continue;
    int beg = nptr[n], end = nptr[n + 1];
    float a[8] = {};
    for (int j = beg; j < end; j++) {
      int e = nhes[j];
      uint4 rv = *(const uint4*)(he + (size_t)e * F + c0);
      acc8(rv, a);
    }
    float inv = (end > beg) ? 1.0f / (float)(end - beg) : 0.0f;
    float cmul = (end > beg) ? 1.0f : 0.0f;   // deg-0 node: +b only
    float o[8];
#pragma unroll
    for (int j = 0; j < 8; j++) {
      o[j] = fmaxf(fmaf(a[j], inv, bb[j] + cmul * cc[j]), 0.f);
      s[j] += o[j]; ss[j] += o[j] * o[j];
    }
    uint4 ov;
    ov.x = pack2(o[0], o[1]); ov.y = pack2(o[2], o[3]);
    ov.z = pack2(o[4], o[5]); ov.w = pack2(o[6], o[7]);
    *(uint4*)(dst + (size_t)n * F + c0) = ov;
  }
  __shared__ float Ls[8][256];
  __shared__ float Lss[8][256];
#pragma unroll
  for (int j = 0; j < 8; j++) { Ls[half][c0 + j] = s[j]; Lss[half][c0 + j] = ss[j]; }
  __syncthreads();
  int c = threadIdx.x;
  float a1 = 0.f, a2 = 0.f;
#pragma unroll
  for (int h = 0; h < 8; h++) { a1 += Ls[h][c]; a2 += Lss[h][c]; }
  atomicAdd(gsum + c, a1);
  atomicAdd(gss + c, a2);
}

// final hyperedge->node, F=128, +b3(+c3 if deg>0), relu, f32 out.
__global__ __launch_bounds__(256) void agg_out(
    const unsigned short* __restrict__ he, const int* __restrict__ nptr,
    const int* __restrict__ nhes, const float* __restrict__ b,
    const float* __restrict__ cvec, float* __restrict__ out) {
  const int F = 128;
  int g = threadIdx.x >> 4, l = threadIdx.x & 15, c0 = l * 8;
  int n = blockIdx.x * 16 + g;
  if (n >= N_NODES) return;
  int beg = nptr[n], end = nptr[n + 1];
  float a[8] = {};
  for (int j = beg; j < end; j++) {
    int e = nhes[j];
    uint4 rv = *(const uint4*)(he + (size_t)e * F + c0);
    acc8(rv, a);
  }
  float inv = (end > beg) ? 1.0f / (float)(end - beg) : 0.0f;
  float cmul = (end > beg) ? 1.0f : 0.0f;
  float4 o0, o1;
  o0.x = fmaxf(fmaf(a[0], inv, b[c0 + 0] + cmul * cvec[c0 + 0]), 0.f);
  o0.y = fmaxf(fmaf(a[1], inv, b[c0 + 1] + cmul * cvec[c0 + 1]), 0.f);
  o0.z = fmaxf(fmaf(a[2], inv, b[c0 + 2] + cmul * cvec[c0 + 2]), 0.f);
  o0.w = fmaxf(fmaf(a[3], inv, b[c0 + 3] + cmul * cvec[c0 + 3]), 0.f);
  o1.x = fmaxf(fmaf(a[4], inv, b[c0 + 4] + cmul * cvec[c0 + 4]), 0.f);
  o1.y = fmaxf(fmaf(a[5], inv, b[c0 + 5] + cmul * cvec[c0 + 5]), 0.f);
  o1.z = fmaxf(fmaf(a[6], inv, b[c0 + 6] + cmul * cvec[c0 + 6]), 0.f);
  o1.w = fmaxf(fmaf(a[7], inv, b[c0 + 7] + cmul * cvec[c0 + 7]), 0.f);
  float* dp = out + (size_t)n * F + c0;
  *(float4*)dp = o0;
  *(float4*)(dp + 4) = o1;
}

// ---------------------------------------------------------------- launch

extern "C" void kernel_launch(void* const* d_in, const int* in_sizes, int n_in,
                              void* d_out, int out_size, void* d_ws, size_t ws_size,
                              hipStream_t stream) {
  const float* x    = (const float*)d_in[0];
  const int*   edge = (const int*)d_in[1];
  const int*   nidx = edge;
  const int*   hidx = edge + N_INC;
  const float* W1  = (const float*)d_in[2];
  const float* b1  = (const float*)d_in[3];
  const float* g1  = (const float*)d_in[4];
  const float* be1 = (const float*)d_in[5];
  const float* W2  = (const float*)d_in[6];
  const float* b2  = (const float*)d_in[7];
  const float* g2  = (const float*)d_in[8];
  const float* be2 = (const float*)d_in[9];
  const float* W3  = (const float*)d_in[10];
  const float* b3  = (const float*)d_in[11];
  float* out = (float*)d_out;

  char* ws = (char*)d_ws;
  size_t off = 0;
  auto alloc = [&](size_t bytes) -> void* {
    void* p = ws + off;
    off = (off + bytes + 255) & ~(size_t)255;
    return p;
  };
  unsigned short* Xb  = (unsigned short*)alloc((size_t)MPAD * 128 * 2);
  unsigned short* Ab  = (unsigned short*)alloc((size_t)MPAD * 256 * 2);
  unsigned short* Bb  = (unsigned short*)alloc((size_t)MPAD * 256 * 2);
  unsigned short* HEb = (unsigned short*)alloc((size_t)N_HE * 256 * 2);
  unsigned short* W1T = (unsigned short*)alloc((size_t)256 * 128 * 2);
  unsigned short* W2T = (unsigned short*)alloc((size_t)256 * 256 * 2);
  unsigned short* W3T = (unsigned short*)alloc((size_t)128 * 256 * 2);
  size_t zero_begin = off;
  int* he_cnt   = (int*)alloc((size_t)N_HE * 4);
  int* node_cnt = (int*)alloc((size_t)N_NODES * 4);
  float* gsum1 = (float*)alloc(1024);
  float* gss1  = (float*)alloc(1024);
  float* gsum2 = (float*)alloc(1024);
  float* gss2  = (float*)alloc(1024);
  float* c1 = (float*)alloc(1024);
  float* c2 = (float*)alloc(1024);
  float* c3 = (float*)alloc(1024);
  size_t zero_end = off;
  int* he_ptr    = (int*)alloc((size_t)(N_HE + 1) * 4);
  int* node_ptr  = (int*)alloc((size_t)(N_NODES + 1) * 4);
  int* he_fill   = (int*)alloc((size_t)N_HE * 4);
  int* node_fill = (int*)alloc((size_t)N_NODES * 4);
  int* he_nodes  = (int*)alloc((size_t)N_INC * 4);
  int* node_hes  = (int*)alloc((size_t)N_INC * 4);
  int* incl      = (int*)alloc((size_t)N_NODES * 4);
  int* bsums     = (int*)alloc(512);
  float* scale1 = (float*)alloc(1024);
  float* shift1 = (float*)alloc(1024);
  float* scale2 = (float*)alloc(1024);
  float* shift2 = (float*)alloc(1024);

  // ---- CSR build ----
  int zero_ints = (int)((zero_end - zero_begin) / 4);
  zero_kernel<<<(zero_ints + 255) / 256, 256, 0, stream>>>(he_cnt, zero_ints);
  count_kernel<<<(N_INC + 255) / 256, 256, 0, stream>>>(nidx, hidx, node_cnt, he_cnt);
  {
    int nb = (N_HE + 1023) / 1024;
    scan1<<<nb, 1024, 0, stream>>>(he_cnt, incl, bsums, N_HE);
    scan2<<<1, 64, 0, stream>>>(bsums, nb);
    scan3<<<nb, 1024, 0, stream>>>(he_cnt, incl, bsums, he_ptr, he_fill, N_HE);
  }
  {
    int nb = (N_NODES + 1023) / 1024;
    scan1<<<nb, 1024, 0, stream>>>(node_cnt, incl, bsums, N_NODES);
    scan2<<<1, 64, 0, stream>>>(bsums, nb);
    scan3<<<nb, 1024, 0, stream>>>(node_cnt, incl, bsums, node_ptr, node_fill, N_NODES);
  }
  fill_kernel<<<(N_INC + 255) / 256, 256, 0, stream>>>(nidx, hidx, node_fill, he_fill,
                                                       node_hes, he_nodes);

  // ---- precompute ----
  convert_x<<<(N_NODES * 16 + 255) / 256, 256, 0, stream>>>(x, Xb);
  { dim3 g(128 / 16, 1); fold_w<<<g, 256, 0, stream>>>(W1, nullptr, nullptr, W1T, c1, 128, 256); }

  const int MB = MPAD / 128;            // 782
  const float invN = 1.0f / (float)N_NODES;

  // ---- layer 1 ----
  { dim3 g(MB, 2); gemm_mfma<<<g, 256, 0, stream>>>(Xb, W1T, Ab, 128, 256); }
  agg_he<<<(N_HE + 7) / 8, 256, 0, stream>>>(Ab, he_ptr, he_nodes, HEb, 256, 5, N_HE);
  node_agg_bn<<<(N_NODES + 31) / 32, 256, 0, stream>>>(HEb, node_ptr, node_hes, b1, c1,
                                                       Bb, gsum1, gss1);
  bn_finalize<<<1, 256, 0, stream>>>(gsum1, gss1, g1, be1, scale1, shift1, invN);

  // ---- layer 2 ----
  { dim3 g(256 / 16, 1); fold_w<<<g, 256, 0, stream>>>(W2, scale1, shift1, W2T, c2, 256, 256); }
  { dim3 g(MB, 2); gemm_mfma<<<g, 256, 0, stream>>>(Bb, W2T, Ab, 256, 256); }
  agg_he<<<(N_HE + 7) / 8, 256, 0, stream>>>(Ab, he_ptr, he_nodes, HEb, 256, 5, N_HE);
  node_agg_bn<<<(N_NODES + 31) / 32, 256, 0, stream>>>(HEb, node_ptr, node_hes, b2, c2,
                                                       Bb, gsum2, gss2);
  bn_finalize<<<1, 256, 0, stream>>>(gsum2, gss2, g2, be2, scale2, shift2, invN);

  // ---- layer 3 ----
  { dim3 g(256 / 16, 1); fold_w<<<g, 256, 0, stream>>>(W3, scale2, shift2, W3T, c3, 256, 128); }
  { dim3 g(MB, 1); gemm_mfma<<<g, 256, 0, stream>>>(Bb, W3T, Ab, 256, 128); }
  agg_he<<<(N_HE + 15) / 16, 256, 0, stream>>>(Ab, he_ptr, he_nodes, HEb, 128, 4, N_HE);
  agg_out<<<(N_NODES + 15) / 16, 256, 0, stream>>>(HEb, node_ptr, node_hes, b3, c3, out);
}

// Round 5
// 566.926 us; speedup vs baseline: 1.0225x; 1.0225x over previous
//
#include <hip/hip_runtime.h>

#define N_NODES 100000
#define N_HE    30000
#define N_INC   300000
#define MPAD    100096          // 782 * 128

typedef short  short8  __attribute__((ext_vector_type(8)));
typedef float  floatx4 __attribute__((ext_vector_type(4)));

__device__ inline unsigned short f2bf(float f) {
  unsigned int u = __float_as_uint(f);
  u = (u + 0x7fff + ((u >> 16) & 1)) >> 16;   // round-to-nearest-even
  return (unsigned short)u;
}
__device__ inline unsigned int pack2(float lo, float hi) {
  return (unsigned int)f2bf(lo) | ((unsigned int)f2bf(hi) << 16);
}
__device__ inline void acc8(uint4 rv, float* a) {
  unsigned int u;
  u = rv.x; a[0] += __uint_as_float(u << 16); a[1] += __uint_as_float(u & 0xffff0000u);
  u = rv.y; a[2] += __uint_as_float(u << 16); a[3] += __uint_as_float(u & 0xffff0000u);
  u = rv.z; a[4] += __uint_as_float(u << 16); a[5] += __uint_as_float(u & 0xffff0000u);
  u = rv.w; a[6] += __uint_as_float(u << 16); a[7] += __uint_as_float(u & 0xffff0000u);
}

// Batched segment gather: up to 4 independent row loads in flight before acc.
// idx clamped for short segments; masked acc avoids double-count.
__device__ inline void gather4(const unsigned short* __restrict__ base,
                               const int* __restrict__ idx, int beg, int end,
                               int F, int c0, float* a) {
  for (int j = beg; j < end; j += 4) {
    int d = end - j;
    int j1 = j + (d > 1 ? 1 : 0);
    int j2 = j + (d > 2 ? 2 : 0);
    int j3 = j + (d > 3 ? 3 : 0);
    int e0 = idx[j], e1 = idx[j1], e2 = idx[j2], e3 = idx[j3];
    uint4 r0 = *(const uint4*)(base + (size_t)e0 * F + c0);
    uint4 r1 = *(const uint4*)(base + (size_t)e1 * F + c0);
    uint4 r2 = *(const uint4*)(base + (size_t)e2 * F + c0);
    uint4 r3 = *(const uint4*)(base + (size_t)e3 * F + c0);
    acc8(r0, a);
    if (d > 1) acc8(r1, a);
    if (d > 2) acc8(r2, a);
    if (d > 3) acc8(r3, a);
  }
}

// ---------------------------------------------------------------- CSR build

__global__ void zero_kernel(int* __restrict__ p, int n) {
  int i = blockIdx.x * blockDim.x + threadIdx.x;
  if (i < n) p[i] = 0;
}

__global__ void count_kernel(const int* __restrict__ nidx, const int* __restrict__ hidx,
                             int* __restrict__ node_cnt, int* __restrict__ he_cnt) {
  int i = blockIdx.x * blockDim.x + threadIdx.x;
  if (i < N_INC) {
    atomicAdd(&node_cnt[nidx[i]], 1);
    atomicAdd(&he_cnt[hidx[i]], 1);
  }
}

__global__ void scan1(const int* __restrict__ cnt, int* __restrict__ incl,
                      int* __restrict__ bsums, int n) {
  __shared__ int tmp[1024];
  int tid = threadIdx.x;
  int i = blockIdx.x * 1024 + tid;
  tmp[tid] = (i < n) ? cnt[i] : 0;
  __syncthreads();
  for (int off = 1; off < 1024; off <<= 1) {
    int t = (tid >= off) ? tmp[tid - off] : 0;
    __syncthreads();
    tmp[tid] += t;
    __syncthreads();
  }
  if (i < n) incl[i] = tmp[tid];
  if (tid == 1023) bsums[blockIdx.x] = tmp[1023];
}

__global__ void scan2(int* __restrict__ bsums, int nb) {
  if (threadIdx.x == 0 && blockIdx.x == 0) {
    int run = 0;
    for (int b = 0; b < nb; b++) { int v = bsums[b]; bsums[b] = run; run += v; }
  }
}

__global__ void scan3(const int* __restrict__ cnt, const int* __restrict__ incl,
                      const int* __restrict__ bsums, int* __restrict__ ptr,
                      int* __restrict__ fill, int n) {
  int i = blockIdx.x * 1024 + threadIdx.x;
  if (i < n) {
    int e = incl[i] - cnt[i] + bsums[blockIdx.x];
    ptr[i] = e;
    fill[i] = e;
    if (i == n - 1) ptr[n] = incl[i] + bsums[blockIdx.x];
  }
}

__global__ void fill_kernel(const int* __restrict__ nidx, const int* __restrict__ hidx,
                            int* __restrict__ node_fill, int* __restrict__ he_fill,
                            int* __restrict__ node_hes, int* __restrict__ he_nodes) {
  int i = blockIdx.x * blockDim.x + threadIdx.x;
  if (i < N_INC) {
    int nn = nidx[i], hh = hidx[i];
    int p1 = atomicAdd(&node_fill[nn], 1);
    node_hes[p1] = hh;
    int p2 = atomicAdd(&he_fill[hh], 1);
    he_nodes[p2] = nn;
  }
}

// ---------------------------------------------------------------- converters / weight fold

__global__ void convert_x(const float* __restrict__ x, unsigned short* __restrict__ xb) {
  int i = blockIdx.x * 256 + threadIdx.x;      // 8 elems per thread
  if (i >= N_NODES * 16) return;
  const float4* p = (const float4*)x + (size_t)i * 2;
  float4 a = p[0], b = p[1];
  uint4 o;
  o.x = pack2(a.x, a.y); o.y = pack2(a.z, a.w);
  o.z = pack2(b.x, b.y); o.w = pack2(b.z, b.w);
  *(uint4*)(xb + (size_t)i * 8) = o;
}

// WT[n][k] = bf16(W[k][n]*scale[k]);  cvec[n] += partial sum_k shift[k]*W[k][n]
__global__ __launch_bounds__(256) void fold_w(
    const float* __restrict__ W, const float* __restrict__ scale,
    const float* __restrict__ shift, unsigned short* __restrict__ WT,
    float* __restrict__ cvec, int K, int N) {
  int n = blockIdx.y * 256 + threadIdx.x;
  if (n >= N) return;
  int k0 = blockIdx.x * 16;
  float c = 0.f;
  unsigned short loc[16];
#pragma unroll
  for (int i = 0; i < 16; i++) {
    int k = k0 + i;
    float w = W[(size_t)k * N + n];
    float s = scale ? scale[k] : 1.f;
    float t = shift ? shift[k] : 0.f;
    loc[i] = f2bf(w * s);
    c += t * w;
  }
  *(uint4*)(WT + (size_t)n * K + k0)     = *(const uint4*)&loc[0];
  *(uint4*)(WT + (size_t)n * K + k0 + 8) = *(const uint4*)&loc[8];
  atomicAdd(cvec + n, c);
}

__global__ void bn_finalize(const float* __restrict__ gsum, const float* __restrict__ gss,
                            const float* __restrict__ g, const float* __restrict__ be,
                            float* __restrict__ scale, float* __restrict__ shift, float invN) {
  int c = threadIdx.x;  // 256
  float m = gsum[c] * invN;
  float v = gss[c] * invN - m * m;
  float sc = g[c] * rsqrtf(v + 1e-5f);
  scale[c] = sc;
  shift[c] = be[c] - m * sc;
}

// BN stats over Bb [N_NODES][256] bf16, streaming coalesced.
// grid 256 x 256 threads; thread: channel pair cp (0..127), row half rh.
__global__ __launch_bounds__(256) void bn_stats(
    const unsigned short* __restrict__ B, float* __restrict__ gsum,
    float* __restrict__ gss) {
  const int cp = threadIdx.x & 127, rh = threadIdx.x >> 7;
  float s0 = 0.f, s1 = 0.f, q0 = 0.f, q1 = 0.f;
  const int base = blockIdx.x * 392;
  for (int i = 0; i < 196; i++) {
    int r = base + 2 * i + rh;
    if (r < N_NODES) {
      unsigned int u = *(const unsigned int*)(B + (size_t)r * 256 + cp * 2);
      float x0 = __uint_as_float(u << 16);
      float x1 = __uint_as_float(u & 0xffff0000u);
      s0 += x0; s1 += x1; q0 += x0 * x0; q1 += x1 * x1;
    }
  }
  __shared__ float S[2][128][2], Q[2][128][2];
  S[rh][cp][0] = s0; S[rh][cp][1] = s1;
  Q[rh][cp][0] = q0; Q[rh][cp][1] = q1;
  __syncthreads();
  if (threadIdx.x < 128) {
    int c = threadIdx.x;
    atomicAdd(gsum + 2 * c,     S[0][c][0] + S[1][c][0]);
    atomicAdd(gsum + 2 * c + 1, S[0][c][1] + S[1][c][1]);
    atomicAdd(gss + 2 * c,      Q[0][c][0] + Q[1][c][0]);
    atomicAdd(gss + 2 * c + 1,  Q[0][c][1] + Q[1][c][1]);
  }
}

// ---------------------------------------------------------------- bf16 MFMA GEMM (m97 pattern)

__global__ __launch_bounds__(256) void gemm_mfma(
    const unsigned short* __restrict__ A, const unsigned short* __restrict__ BT,
    unsigned short* __restrict__ C, int K, int N) {
  __shared__ unsigned short As[128 * 32];
  __shared__ unsigned short Bs[128 * 32];
  const int tid  = threadIdx.x;
  const int w    = tid >> 6, lane = tid & 63;
  const int wm   = w & 1,  wn   = w >> 1;
  const int bm   = blockIdx.x * 128, bn = blockIdx.y * 128;
  const int quad = lane >> 4, r16 = lane & 15;

  floatx4 acc[4][4] = {};

  const int srow = (lane >> 2);
  const int scol = (lane & 3) * 8;

  for (int kb = 0; kb < K; kb += 32) {
#pragma unroll
    for (int i = 0; i < 2; i++) {
      const int row = (w * 2 + i) * 16 + srow;
      const unsigned short* ga = A  + (size_t)(bm + row) * K + kb + scol;
      const unsigned short* gb = BT + (size_t)(bn + row) * K + kb + scol;
      __builtin_amdgcn_global_load_lds(
          (const __attribute__((address_space(1))) void*)ga,
          (__attribute__((address_space(3))) void*)(&As[(w * 2 + i) * 512]), 16, 0, 0);
      __builtin_amdgcn_global_load_lds(
          (const __attribute__((address_space(1))) void*)gb,
          (__attribute__((address_space(3))) void*)(&Bs[(w * 2 + i) * 512]), 16, 0, 0);
    }
    __syncthreads();
    short8 af[4], bfr[4];
#pragma unroll
    for (int t = 0; t < 4; t++) {
      af[t]  = *(const short8*)&As[(wm * 64 + t * 16 + r16) * 32 + quad * 8];
      bfr[t] = *(const short8*)&Bs[(wn * 64 + t * 16 + r16) * 32 + quad * 8];
    }
#pragma unroll
    for (int mi = 0; mi < 4; mi++)
#pragma unroll
      for (int ni = 0; ni < 4; ni++)
        acc[mi][ni] = __builtin_amdgcn_mfma_f32_16x16x32_bf16(af[mi], bfr[ni], acc[mi][ni], 0, 0, 0);
    __syncthreads();
  }
#pragma unroll
  for (int mi = 0; mi < 4; mi++)
#pragma unroll
    for (int ni = 0; ni < 4; ni++)
#pragma unroll
      for (int rr = 0; rr < 4; rr++) {
        int gm = bm + wm * 64 + mi * 16 + quad * 4 + rr;
        int gn = bn + wn * 64 + ni * 16 + r16;
        C[(size_t)gm * N + gn] = f2bf(acc[mi][ni][rr]);
      }
}

// ---------------------------------------------------------------- aggregations (bf16 in/out)

// node -> hyperedge mean. F/8 lanes per segment; shift = log2(F/8). 4-deep batched.
__global__ __launch_bounds__(256) void agg_he(
    const unsigned short* __restrict__ src, const int* __restrict__ ptr,
    const int* __restrict__ idx, unsigned short* __restrict__ dst,
    int F, int shift, int nSeg) {
  int seg = blockIdx.x * (256 >> shift) + (threadIdx.x >> shift);
  if (seg >= nSeg) return;
  int l = threadIdx.x & ((1 << shift) - 1);
  int c0 = l * 8;
  int beg = ptr[seg], end = ptr[seg + 1];
  float a[8] = {};
  gather4(src, idx, beg, end, F, c0, a);
  float inv = (end > beg) ? 1.0f / (float)(end - beg) : 0.0f;
  uint4 o;
  o.x = pack2(a[0] * inv, a[1] * inv);
  o.y = pack2(a[2] * inv, a[3] * inv);
  o.z = pack2(a[4] * inv, a[5] * inv);
  o.w = pack2(a[6] * inv, a[7] * inv);
  *(uint4*)(dst + (size_t)seg * F + c0) = o;
}

// hyperedge -> node, F=256, fused bias(+cvec if deg>0) + relu. bf16 out. No stats.
// 64 nodes/block: 8 groups of 32 lanes x 8 nodes.
__global__ __launch_bounds__(256) void node_agg(
    const unsigned short* __restrict__ he, const int* __restrict__ nptr,
    const int* __restrict__ nhes, const float* __restrict__ b,
    const float* __restrict__ cvec, unsigned short* __restrict__ dst) {
  const int F = 256;
  const int grp = threadIdx.x >> 5, l = threadIdx.x & 31, c0 = l * 8;
  float bb[8], cc[8];
#pragma unroll
  for (int j = 0; j < 8; j++) { bb[j] = b[c0 + j]; cc[j] = cvec[c0 + j]; }
  for (int i = 0; i < 8; i++) {
    int n = blockIdx.x * 64 + i * 8 + grp;
    if (n >= N_NODES) continue;
    int beg = nptr[n], end = nptr[n + 1];
    float a[8] = {};
    gather4(he, nhes, beg, end, F, c0, a);
    float inv = (end > beg) ? 1.0f / (float)(end - beg) : 0.0f;
    float cmul = (end > beg) ? 1.0f : 0.0f;   // deg-0 node: +b only
    float o[8];
#pragma unroll
    for (int j = 0; j < 8; j++)
      o[j] = fmaxf(fmaf(a[j], inv, bb[j] + cmul * cc[j]), 0.f);
    uint4 ov;
    ov.x = pack2(o[0], o[1]); ov.y = pack2(o[2], o[3]);
    ov.z = pack2(o[4], o[5]); ov.w = pack2(o[6], o[7]);
    *(uint4*)(dst + (size_t)n * F + c0) = ov;
  }
}

// final hyperedge -> node, F=128, +b3(+c3 if deg>0), relu, f32 out. 4-deep batched.
__global__ __launch_bounds__(256) void agg_out(
    const unsigned short* __restrict__ he, const int* __restrict__ nptr,
    const int* __restrict__ nhes, const float* __restrict__ b,
    const float* __restrict__ cvec, float* __restrict__ out) {
  const int F = 128;
  int g = threadIdx.x >> 4, l = threadIdx.x & 15, c0 = l * 8;
  int n = blockIdx.x * 16 + g;
  if (n >= N_NODES) return;
  int beg = nptr[n], end = nptr[n + 1];
  float a[8] = {};
  gather4(he, nhes, beg, end, F, c0, a);
  float inv = (end > beg) ? 1.0f / (float)(end - beg) : 0.0f;
  float cmul = (end > beg) ? 1.0f : 0.0f;
  float4 o0, o1;
  o0.x = fmaxf(fmaf(a[0], inv, b[c0 + 0] + cmul * cvec[c0 + 0]), 0.f);
  o0.y = fmaxf(fmaf(a[1], inv, b[c0 + 1] + cmul * cvec[c0 + 1]), 0.f);
  o0.z = fmaxf(fmaf(a[2], inv, b[c0 + 2] + cmul * cvec[c0 + 2]), 0.f);
  o0.w = fmaxf(fmaf(a[3], inv, b[c0 + 3] + cmul * cvec[c0 + 3]), 0.f);
  o1.x = fmaxf(fmaf(a[4], inv, b[c0 + 4] + cmul * cvec[c0 + 4]), 0.f);
  o1.y = fmaxf(fmaf(a[5], inv, b[c0 + 5] + cmul * cvec[c0 + 5]), 0.f);
  o1.z = fmaxf(fmaf(a[6], inv, b[c0 + 6] + cmul * cvec[c0 + 6]), 0.f);
  o1.w = fmaxf(fmaf(a[7], inv, b[c0 + 7] + cmul * cvec[c0 + 7]), 0.f);
  float* dp = out + (size_t)n * F + c0;
  *(float4*)dp = o0;
  *(float4*)(dp + 4) = o1;
}

// ---------------------------------------------------------------- launch

extern "C" void kernel_launch(void* const* d_in, const int* in_sizes, int n_in,
                              void* d_out, int out_size, void* d_ws, size_t ws_size,
                              hipStream_t stream) {
  const float* x    = (const float*)d_in[0];
  const int*   edge = (const int*)d_in[1];
  const int*   nidx = edge;
  const int*   hidx = edge + N_INC;
  const float* W1  = (const float*)d_in[2];
  const float* b1  = (const float*)d_in[3];
  const float* g1  = (const float*)d_in[4];
  const float* be1 = (const float*)d_in[5];
  const float* W2  = (const float*)d_in[6];
  const float* b2  = (const float*)d_in[7];
  const float* g2  = (const float*)d_in[8];
  const float* be2 = (const float*)d_in[9];
  const float* W3  = (const float*)d_in[10];
  const float* b3  = (const float*)d_in[11];
  float* out = (float*)d_out;

  char* ws = (char*)d_ws;
  size_t off = 0;
  auto alloc = [&](size_t bytes) -> void* {
    void* p = ws + off;
    off = (off + bytes + 255) & ~(size_t)255;
    return p;
  };
  unsigned short* Xb  = (unsigned short*)alloc((size_t)MPAD * 128 * 2);
  unsigned short* Ab  = (unsigned short*)alloc((size_t)MPAD * 256 * 2);
  unsigned short* Bb  = (unsigned short*)alloc((size_t)MPAD * 256 * 2);
  unsigned short* HEb = (unsigned short*)alloc((size_t)N_HE * 256 * 2);
  unsigned short* W1T = (unsigned short*)alloc((size_t)256 * 128 * 2);
  unsigned short* W2T = (unsigned short*)alloc((size_t)256 * 256 * 2);
  unsigned short* W3T = (unsigned short*)alloc((size_t)128 * 256 * 2);
  size_t zero_begin = off;
  int* he_cnt   = (int*)alloc((size_t)N_HE * 4);
  int* node_cnt = (int*)alloc((size_t)N_NODES * 4);
  float* gsum1 = (float*)alloc(1024);
  float* gss1  = (float*)alloc(1024);
  float* gsum2 = (float*)alloc(1024);
  float* gss2  = (float*)alloc(1024);
  float* c1 = (float*)alloc(1024);
  float* c2 = (float*)alloc(1024);
  float* c3 = (float*)alloc(1024);
  size_t zero_end = off;
  int* he_ptr    = (int*)alloc((size_t)(N_HE + 1) * 4);
  int* node_ptr  = (int*)alloc((size_t)(N_NODES + 1) * 4);
  int* he_fill   = (int*)alloc((size_t)N_HE * 4);
  int* node_fill = (int*)alloc((size_t)N_NODES * 4);
  int* he_nodes  = (int*)alloc((size_t)N_INC * 4);
  int* node_hes  = (int*)alloc((size_t)N_INC * 4);
  int* incl      = (int*)alloc((size_t)N_NODES * 4);
  int* bsums     = (int*)alloc(512);
  float* scale1 = (float*)alloc(1024);
  float* shift1 = (float*)alloc(1024);
  float* scale2 = (float*)alloc(1024);
  float* shift2 = (float*)alloc(1024);

  // ---- CSR build ----
  int zero_ints = (int)((zero_end - zero_begin) / 4);
  zero_kernel<<<(zero_ints + 255) / 256, 256, 0, stream>>>(he_cnt, zero_ints);
  count_kernel<<<(N_INC + 255) / 256, 256, 0, stream>>>(nidx, hidx, node_cnt, he_cnt);
  {
    int nb = (N_HE + 1023) / 1024;
    scan1<<<nb, 1024, 0, stream>>>(he_cnt, incl, bsums, N_HE);
    scan2<<<1, 64, 0, stream>>>(bsums, nb);
    scan3<<<nb, 1024, 0, stream>>>(he_cnt, incl, bsums, he_ptr, he_fill, N_HE);
  }
  {
    int nb = (N_NODES + 1023) / 1024;
    scan1<<<nb, 1024, 0, stream>>>(node_cnt, incl, bsums, N_NODES);
    scan2<<<1, 64, 0, stream>>>(bsums, nb);
    scan3<<<nb, 1024, 0, stream>>>(node_cnt, incl, bsums, node_ptr, node_fill, N_NODES);
  }
  fill_kernel<<<(N_INC + 255) / 256, 256, 0, stream>>>(nidx, hidx, node_fill, he_fill,
                                                       node_hes, he_nodes);

  // ---- precompute ----
  convert_x<<<(N_NODES * 16 + 255) / 256, 256, 0, stream>>>(x, Xb);
  { dim3 g(128 / 16, 1); fold_w<<<g, 256, 0, stream>>>(W1, nullptr, nullptr, W1T, c1, 128, 256); }

  const int MB = MPAD / 128;            // 782
  const float invN = 1.0f / (float)N_NODES;

  // ---- layer 1 ----
  { dim3 g(MB, 2); gemm_mfma<<<g, 256, 0, stream>>>(Xb, W1T, Ab, 128, 256); }
  agg_he<<<(N_HE + 7) / 8, 256, 0, stream>>>(Ab, he_ptr, he_nodes, HEb, 256, 5, N_HE);
  node_agg<<<(N_NODES + 63) / 64, 256, 0, stream>>>(HEb, node_ptr, node_hes, b1, c1, Bb);
  bn_stats<<<256, 256, 0, stream>>>(Bb, gsum1, gss1);
  bn_finalize<<<1, 256, 0, stream>>>(gsum1, gss1, g1, be1, scale1, shift1, invN);

  // ---- layer 2 ----
  { dim3 g(256 / 16, 1); fold_w<<<g, 256, 0, stream>>>(W2, scale1, shift1, W2T, c2, 256, 256); }
  { dim3 g(MB, 2); gemm_mfma<<<g, 256, 0, stream>>>(Bb, W2T, Ab, 256, 256); }
  agg_he<<<(N_HE + 7) / 8, 256, 0, stream>>>(Ab, he_ptr, he_nodes, HEb, 256, 5, N_HE);
  node_agg<<<(N_NODES + 63) / 64, 256, 0, stream>>>(HEb, node_ptr, node_hes, b2, c2, Bb);
  bn_stats<<<256, 256, 0, stream>>>(Bb, gsum2, gss2);
  bn_finalize<<<1, 256, 0, stream>>>(gsum2, gss2, g2, be2, scale2, shift2, invN);

  // ---- layer 3 ----
  { dim3 g(256 / 16, 1); fold_w<<<g, 256, 0, stream>>>(W3, scale2, shift2, W3T, c3, 256, 128); }
  { dim3 g(MB, 1); gemm_mfma<<<g, 256, 0, stream>>>(Bb, W3T, Ab, 256, 128); }
  agg_he<<<(N_HE + 15) / 16, 256, 0, stream>>>(Ab, he_ptr, he_nodes, HEb, 128, 4, N_HE);
  agg_out<<<(N_NODES + 15) / 16, 256, 0, stream>>>(HEb, node_ptr, node_hes, b3, c3, out);
}

// Round 6
// 524.378 us; speedup vs baseline: 1.1055x; 1.0811x over previous
//
#include <hip/hip_runtime.h>

#define N_NODES 100000
#define N_HE    30000
#define N_INC   300000
#define MPAD    100096          // 782 * 128

typedef short  short8  __attribute__((ext_vector_type(8)));
typedef float  floatx4 __attribute__((ext_vector_type(4)));

__device__ inline unsigned short f2bf(float f) {
  unsigned int u = __float_as_uint(f);
  u = (u + 0x7fff + ((u >> 16) & 1)) >> 16;   // round-to-nearest-even
  return (unsigned short)u;
}
__device__ inline unsigned int pack2(float lo, float hi) {
  return (unsigned int)f2bf(lo) | ((unsigned int)f2bf(hi) << 16);
}
__device__ inline void acc8(uint4 rv, float* a) {
  unsigned int u;
  u = rv.x; a[0] += __uint_as_float(u << 16); a[1] += __uint_as_float(u & 0xffff0000u);
  u = rv.y; a[2] += __uint_as_float(u << 16); a[3] += __uint_as_float(u & 0xffff0000u);
  u = rv.z; a[4] += __uint_as_float(u << 16); a[5] += __uint_as_float(u & 0xffff0000u);
  u = rv.w; a[6] += __uint_as_float(u << 16); a[7] += __uint_as_float(u & 0xffff0000u);
}

// Batched segment gather: up to 4 independent row loads in flight before acc.
__device__ inline void gather4(const unsigned short* __restrict__ base,
                               const int* __restrict__ idx, int beg, int end,
                               int F, int c0, float* a) {
  for (int j = beg; j < end; j += 4) {
    int d = end - j;
    int j1 = j + (d > 1 ? 1 : 0);
    int j2 = j + (d > 2 ? 2 : 0);
    int j3 = j + (d > 3 ? 3 : 0);
    int e0 = idx[j], e1 = idx[j1], e2 = idx[j2], e3 = idx[j3];
    uint4 r0 = *(const uint4*)(base + (size_t)e0 * F + c0);
    uint4 r1 = *(const uint4*)(base + (size_t)e1 * F + c0);
    uint4 r2 = *(const uint4*)(base + (size_t)e2 * F + c0);
    uint4 r3 = *(const uint4*)(base + (size_t)e3 * F + c0);
    acc8(r0, a);
    if (d > 1) acc8(r1, a);
    if (d > 2) acc8(r2, a);
    if (d > 3) acc8(r3, a);
  }
}

// ---------------------------------------------------------------- CSR build

__global__ void zero_kernel(int* __restrict__ p, int n) {
  int i = blockIdx.x * blockDim.x + threadIdx.x;
  if (i < n) p[i] = 0;
}

__global__ void count_kernel(const int* __restrict__ nidx, const int* __restrict__ hidx,
                             int* __restrict__ node_cnt, int* __restrict__ he_cnt) {
  int i = blockIdx.x * blockDim.x + threadIdx.x;
  if (i < N_INC) {
    atomicAdd(&node_cnt[nidx[i]], 1);
    atomicAdd(&he_cnt[hidx[i]], 1);
  }
}

__global__ void scan1(const int* __restrict__ cnt, int* __restrict__ incl,
                      int* __restrict__ bsums, int n) {
  __shared__ int tmp[1024];
  int tid = threadIdx.x;
  int i = blockIdx.x * 1024 + tid;
  tmp[tid] = (i < n) ? cnt[i] : 0;
  __syncthreads();
  for (int off = 1; off < 1024; off <<= 1) {
    int t = (tid >= off) ? tmp[tid - off] : 0;
    __syncthreads();
    tmp[tid] += t;
    __syncthreads();
  }
  if (i < n) incl[i] = tmp[tid];
  if (tid == 1023) bsums[blockIdx.x] = tmp[1023];
}

__global__ void scan2(int* __restrict__ bsums, int nb) {
  if (threadIdx.x == 0 && blockIdx.x == 0) {
    int run = 0;
    for (int b = 0; b < nb; b++) { int v = bsums[b]; bsums[b] = run; run += v; }
  }
}

__global__ void scan3(const int* __restrict__ cnt, const int* __restrict__ incl,
                      const int* __restrict__ bsums, int* __restrict__ ptr,
                      int* __restrict__ fill, int n) {
  int i = blockIdx.x * 1024 + threadIdx.x;
  if (i < n) {
    int e = incl[i] - cnt[i] + bsums[blockIdx.x];
    ptr[i] = e;
    fill[i] = e;
    if (i == n - 1) ptr[n] = incl[i] + bsums[blockIdx.x];
  }
}

__global__ void fill_kernel(const int* __restrict__ nidx, const int* __restrict__ hidx,
                            int* __restrict__ node_fill, int* __restrict__ he_fill,
                            int* __restrict__ node_hes, int* __restrict__ he_nodes) {
  int i = blockIdx.x * blockDim.x + threadIdx.x;
  if (i < N_INC) {
    int nn = nidx[i], hh = hidx[i];
    int p1 = atomicAdd(&node_fill[nn], 1);
    node_hes[p1] = hh;
    int p2 = atomicAdd(&he_fill[hh], 1);
    he_nodes[p2] = nn;
  }
}

// ---------------------------------------------------------------- converters / weight fold

__global__ void convert_x(const float* __restrict__ x, unsigned short* __restrict__ xb) {
  int i = blockIdx.x * 256 + threadIdx.x;      // 8 elems per thread
  if (i >= N_NODES * 16) return;
  const float4* p = (const float4*)x + (size_t)i * 2;
  float4 a = p[0], b = p[1];
  uint4 o;
  o.x = pack2(a.x, a.y); o.y = pack2(a.z, a.w);
  o.z = pack2(b.x, b.y); o.w = pack2(b.z, b.w);
  *(uint4*)(xb + (size_t)i * 8) = o;
}

// WT[n][k] = bf16(W[k][n]*scale[k]);  cvec[n] += partial sum_k shift[k]*W[k][n]
__global__ __launch_bounds__(256) void fold_w(
    const float* __restrict__ W, const float* __restrict__ scale,
    const float* __restrict__ shift, unsigned short* __restrict__ WT,
    float* __restrict__ cvec, int K, int N) {
  int n = blockIdx.y * 256 + threadIdx.x;
  if (n >= N) return;
  int k0 = blockIdx.x * 16;
  float c = 0.f;
  unsigned short loc[16];
#pragma unroll
  for (int i = 0; i < 16; i++) {
    int k = k0 + i;
    float w = W[(size_t)k * N + n];
    float s = scale ? scale[k] : 1.f;
    float t = shift ? shift[k] : 0.f;
    loc[i] = f2bf(w * s);
    c += t * w;
  }
  *(uint4*)(WT + (size_t)n * K + k0)     = *(const uint4*)&loc[0];
  *(uint4*)(WT + (size_t)n * K + k0 + 8) = *(const uint4*)&loc[8];
  atomicAdd(cvec + n, c);
}

__global__ void bn_finalize(const float* __restrict__ gsum, const float* __restrict__ gss,
                            const float* __restrict__ g, const float* __restrict__ be,
                            float* __restrict__ scale, float* __restrict__ shift, float invN) {
  int c = threadIdx.x;  // 256
  float m = gsum[c] * invN;
  float v = gss[c] * invN - m * m;
  float sc = g[c] * rsqrtf(v + 1e-5f);
  scale[c] = sc;
  shift[c] = be[c] - m * sc;
}

// ---------------------------------------------------------------- bf16 MFMA GEMM (m97 pattern)

__global__ __launch_bounds__(256) void gemm_mfma(
    const unsigned short* __restrict__ A, const unsigned short* __restrict__ BT,
    unsigned short* __restrict__ C, int K, int N) {
  __shared__ unsigned short As[128 * 32];
  __shared__ unsigned short Bs[128 * 32];
  const int tid  = threadIdx.x;
  const int w    = tid >> 6, lane = tid & 63;
  const int wm   = w & 1,  wn   = w >> 1;
  const int bm   = blockIdx.x * 128, bn = blockIdx.y * 128;
  const int quad = lane >> 4, r16 = lane & 15;

  floatx4 acc[4][4] = {};

  const int srow = (lane >> 2);
  const int scol = (lane & 3) * 8;

  for (int kb = 0; kb < K; kb += 32) {
#pragma unroll
    for (int i = 0; i < 2; i++) {
      const int row = (w * 2 + i) * 16 + srow;
      const unsigned short* ga = A  + (size_t)(bm + row) * K + kb + scol;
      const unsigned short* gb = BT + (size_t)(bn + row) * K + kb + scol;
      __builtin_amdgcn_global_load_lds(
          (const __attribute__((address_space(1))) void*)ga,
          (__attribute__((address_space(3))) void*)(&As[(w * 2 + i) * 512]), 16, 0, 0);
      __builtin_amdgcn_global_load_lds(
          (const __attribute__((address_space(1))) void*)gb,
          (__attribute__((address_space(3))) void*)(&Bs[(w * 2 + i) * 512]), 16, 0, 0);
    }
    __syncthreads();
    short8 af[4], bfr[4];
#pragma unroll
    for (int t = 0; t < 4; t++) {
      af[t]  = *(const short8*)&As[(wm * 64 + t * 16 + r16) * 32 + quad * 8];
      bfr[t] = *(const short8*)&Bs[(wn * 64 + t * 16 + r16) * 32 + quad * 8];
    }
#pragma unroll
    for (int mi = 0; mi < 4; mi++)
#pragma unroll
      for (int ni = 0; ni < 4; ni++)
        acc[mi][ni] = __builtin_amdgcn_mfma_f32_16x16x32_bf16(af[mi], bfr[ni], acc[mi][ni], 0, 0, 0);
    __syncthreads();
  }
#pragma unroll
  for (int mi = 0; mi < 4; mi++)
#pragma unroll
    for (int ni = 0; ni < 4; ni++)
#pragma unroll
      for (int rr = 0; rr < 4; rr++) {
        int gm = bm + wm * 64 + mi * 16 + quad * 4 + rr;
        int gn = bn + wn * 64 + ni * 16 + r16;
        C[(size_t)gm * N + gn] = f2bf(acc[mi][ni][rr]);
      }
}

// ---------------------------------------------------------------- aggregations (bf16 in/out)

// node -> hyperedge mean. F/8 lanes per segment; shift = log2(F/8). 4-deep batched.
__global__ __launch_bounds__(256) void agg_he(
    const unsigned short* __restrict__ src, const int* __restrict__ ptr,
    const int* __restrict__ idx, unsigned short* __restrict__ dst,
    int F, int shift, int nSeg) {
  int seg = blockIdx.x * (256 >> shift) + (threadIdx.x >> shift);
  if (seg >= nSeg) return;
  int l = threadIdx.x & ((1 << shift) - 1);
  int c0 = l * 8;
  int beg = ptr[seg], end = ptr[seg + 1];
  float a[8] = {};
  gather4(src, idx, beg, end, F, c0, a);
  float inv = (end > beg) ? 1.0f / (float)(end - beg) : 0.0f;
  uint4 o;
  o.x = pack2(a[0] * inv, a[1] * inv);
  o.y = pack2(a[2] * inv, a[3] * inv);
  o.z = pack2(a[4] * inv, a[5] * inv);
  o.w = pack2(a[6] * inv, a[7] * inv);
  *(uint4*)(dst + (size_t)seg * F + c0) = o;
}

// hyperedge -> node, F=256: gather4 + bias(+cvec if deg>0) + relu + fused BN stats.
// 64 nodes/block (8 groups of 32 lanes x 8 nodes), grid 1563.
__global__ __launch_bounds__(256) void node_agg_bn(
    const unsigned short* __restrict__ he, const int* __restrict__ nptr,
    const int* __restrict__ nhes, const float* __restrict__ b,
    const float* __restrict__ cvec, unsigned short* __restrict__ dst,
    float* __restrict__ gsum, float* __restrict__ gss) {
  const int F = 256;
  const int grp = threadIdx.x >> 5, l = threadIdx.x & 31, c0 = l * 8;
  float bb[8], cc[8];
#pragma unroll
  for (int j = 0; j < 8; j++) { bb[j] = b[c0 + j]; cc[j] = cvec[c0 + j]; }
  float s[8] = {}, ss[8] = {};
  for (int i = 0; i < 8; i++) {
    int n = blockIdx.x * 64 + i * 8 + grp;
    if (n >= N_NODES) continue;
    int beg = nptr[n], end = nptr[n + 1];
    float a[8] = {};
    gather4(he, nhes, beg, end, F, c0, a);
    float inv = (end > beg) ? 1.0f / (float)(end - beg) : 0.0f;
    float cmul = (end > beg) ? 1.0f : 0.0f;   // deg-0 node: +b only
    float o[8];
#pragma unroll
    for (int j = 0; j < 8; j++) {
      o[j] = fmaxf(fmaf(a[j], inv, bb[j] + cmul * cc[j]), 0.f);
      s[j] += o[j]; ss[j] += o[j] * o[j];
    }
    uint4 ov;
    ov.x = pack2(o[0], o[1]); ov.y = pack2(o[2], o[3]);
    ov.z = pack2(o[4], o[5]); ov.w = pack2(o[6], o[7]);
    *(uint4*)(dst + (size_t)n * F + c0) = ov;
  }
  __shared__ float Ls[8][256];
  __shared__ float Lss[8][256];
#pragma unroll
  for (int j = 0; j < 8; j++) { Ls[grp][c0 + j] = s[j]; Lss[grp][c0 + j] = ss[j]; }
  __syncthreads();
  int c = threadIdx.x;
  float a1 = 0.f, a2 = 0.f;
#pragma unroll
  for (int h = 0; h < 8; h++) { a1 += Ls[h][c]; a2 += Lss[h][c]; }
  atomicAdd(gsum + c, a1);
  atomicAdd(gss + c, a2);
}

// final hyperedge -> node, F=128, +b3(+c3 if deg>0), relu, f32 out. 4-deep batched.
__global__ __launch_bounds__(256) void agg_out(
    const unsigned short* __restrict__ he, const int* __restrict__ nptr,
    const int* __restrict__ nhes, const float* __restrict__ b,
    const float* __restrict__ cvec, float* __restrict__ out) {
  const int F = 128;
  int g = threadIdx.x >> 4, l = threadIdx.x & 15, c0 = l * 8;
  int n = blockIdx.x * 16 + g;
  if (n >= N_NODES) return;
  int beg = nptr[n], end = nptr[n + 1];
  float a[8] = {};
  gather4(he, nhes, beg, end, F, c0, a);
  float inv = (end > beg) ? 1.0f / (float)(end - beg) : 0.0f;
  float cmul = (end > beg) ? 1.0f : 0.0f;
  float4 o0, o1;
  o0.x = fmaxf(fmaf(a[0], inv, b[c0 + 0] + cmul * cvec[c0 + 0]), 0.f);
  o0.y = fmaxf(fmaf(a[1], inv, b[c0 + 1] + cmul * cvec[c0 + 1]), 0.f);
  o0.z = fmaxf(fmaf(a[2], inv, b[c0 + 2] + cmul * cvec[c0 + 2]), 0.f);
  o0.w = fmaxf(fmaf(a[3], inv, b[c0 + 3] + cmul * cvec[c0 + 3]), 0.f);
  o1.x = fmaxf(fmaf(a[4], inv, b[c0 + 4] + cmul * cvec[c0 + 4]), 0.f);
  o1.y = fmaxf(fmaf(a[5], inv, b[c0 + 5] + cmul * cvec[c0 + 5]), 0.f);
  o1.z = fmaxf(fmaf(a[6], inv, b[c0 + 6] + cmul * cvec[c0 + 6]), 0.f);
  o1.w = fmaxf(fmaf(a[7], inv, b[c0 + 7] + cmul * cvec[c0 + 7]), 0.f);
  float* dp = out + (size_t)n * F + c0;
  *(float4*)dp = o0;
  *(float4*)(dp + 4) = o1;
}

// ---------------------------------------------------------------- launch

extern "C" void kernel_launch(void* const* d_in, const int* in_sizes, int n_in,
                              void* d_out, int out_size, void* d_ws, size_t ws_size,
                              hipStream_t stream) {
  const float* x    = (const float*)d_in[0];
  const int*   edge = (const int*)d_in[1];
  const int*   nidx = edge;
  const int*   hidx = edge + N_INC;
  const float* W1  = (const float*)d_in[2];
  const float* b1  = (const float*)d_in[3];
  const float* g1  = (const float*)d_in[4];
  const float* be1 = (const float*)d_in[5];
  const float* W2  = (const float*)d_in[6];
  const float* b2  = (const float*)d_in[7];
  const float* g2  = (const float*)d_in[8];
  const float* be2 = (const float*)d_in[9];
  const float* W3  = (const float*)d_in[10];
  const float* b3  = (const float*)d_in[11];
  float* out = (float*)d_out;

  char* ws = (char*)d_ws;
  size_t off = 0;
  auto alloc = [&](size_t bytes) -> void* {
    void* p = ws + off;
    off = (off + bytes + 255) & ~(size_t)255;
    return p;
  };
  unsigned short* Xb  = (unsigned short*)alloc((size_t)MPAD * 128 * 2);
  unsigned short* Ab  = (unsigned short*)alloc((size_t)MPAD * 256 * 2);
  unsigned short* Bb  = (unsigned short*)alloc((size_t)MPAD * 256 * 2);
  unsigned short* HEb = (unsigned short*)alloc((size_t)N_HE * 256 * 2);
  unsigned short* W1T = (unsigned short*)alloc((size_t)256 * 128 * 2);
  unsigned short* W2T = (unsigned short*)alloc((size_t)256 * 256 * 2);
  unsigned short* W3T = (unsigned short*)alloc((size_t)128 * 256 * 2);
  size_t zero_begin = off;
  int* he_cnt   = (int*)alloc((size_t)N_HE * 4);
  int* node_cnt = (int*)alloc((size_t)N_NODES * 4);
  float* gsum1 = (float*)alloc(1024);
  float* gss1  = (float*)alloc(1024);
  float* gsum2 = (float*)alloc(1024);
  float* gss2  = (float*)alloc(1024);
  float* c1 = (float*)alloc(1024);
  float* c2 = (float*)alloc(1024);
  float* c3 = (float*)alloc(1024);
  size_t zero_end = off;
  int* he_ptr    = (int*)alloc((size_t)(N_HE + 1) * 4);
  int* node_ptr  = (int*)alloc((size_t)(N_NODES + 1) * 4);
  int* he_fill   = (int*)alloc((size_t)N_HE * 4);
  int* node_fill = (int*)alloc((size_t)N_NODES * 4);
  int* he_nodes  = (int*)alloc((size_t)N_INC * 4);
  int* node_hes  = (int*)alloc((size_t)N_INC * 4);
  int* incl      = (int*)alloc((size_t)N_NODES * 4);
  int* bsums     = (int*)alloc(512);
  float* scale1 = (float*)alloc(1024);
  float* shift1 = (float*)alloc(1024);
  float* scale2 = (float*)alloc(1024);
  float* shift2 = (float*)alloc(1024);

  // ---- CSR build ----
  int zero_ints = (int)((zero_end - zero_begin) / 4);
  zero_kernel<<<(zero_ints + 255) / 256, 256, 0, stream>>>(he_cnt, zero_ints);
  count_kernel<<<(N_INC + 255) / 256, 256, 0, stream>>>(nidx, hidx, node_cnt, he_cnt);
  {
    int nb = (N_HE + 1023) / 1024;
    scan1<<<nb, 1024, 0, stream>>>(he_cnt, incl, bsums, N_HE);
    scan2<<<1, 64, 0, stream>>>(bsums, nb);
    scan3<<<nb, 1024, 0, stream>>>(he_cnt, incl, bsums, he_ptr, he_fill, N_HE);
  }
  {
    int nb = (N_NODES + 1023) / 1024;
    scan1<<<nb, 1024, 0, stream>>>(node_cnt, incl, bsums, N_NODES);
    scan2<<<1, 64, 0, stream>>>(bsums, nb);
    scan3<<<nb, 1024, 0, stream>>>(node_cnt, incl, bsums, node_ptr, node_fill, N_NODES);
  }
  fill_kernel<<<(N_INC + 255) / 256, 256, 0, stream>>>(nidx, hidx, node_fill, he_fill,
                                                       node_hes, he_nodes);

  // ---- precompute ----
  convert_x<<<(N_NODES * 16 + 255) / 256, 256, 0, stream>>>(x, Xb);
  { dim3 g(128 / 16, 1); fold_w<<<g, 256, 0, stream>>>(W1, nullptr, nullptr, W1T, c1, 128, 256); }

  const int MB = MPAD / 128;            // 782
  const float invN = 1.0f / (float)N_NODES;

  // ---- layer 1 ----
  { dim3 g(MB, 2); gemm_mfma<<<g, 256, 0, stream>>>(Xb, W1T, Ab, 128, 256); }
  agg_he<<<(N_HE + 7) / 8, 256, 0, stream>>>(Ab, he_ptr, he_nodes, HEb, 256, 5, N_HE);
  node_agg_bn<<<(N_NODES + 63) / 64, 256, 0, stream>>>(HEb, node_ptr, node_hes, b1, c1,
                                                       Bb, gsum1, gss1);
  bn_finalize<<<1, 256, 0, stream>>>(gsum1, gss1, g1, be1, scale1, shift1, invN);

  // ---- layer 2 ----
  { dim3 g(256 / 16, 1); fold_w<<<g, 256, 0, stream>>>(W2, scale1, shift1, W2T, c2, 256, 256); }
  { dim3 g(MB, 2); gemm_mfma<<<g, 256, 0, stream>>>(Bb, W2T, Ab, 256, 256); }
  agg_he<<<(N_HE + 7) / 8, 256, 0, stream>>>(Ab, he_ptr, he_nodes, HEb, 256, 5, N_HE);
  node_agg_bn<<<(N_NODES + 63) / 64, 256, 0, stream>>>(HEb, node_ptr, node_hes, b2, c2,
                                                       Bb, gsum2, gss2);
  bn_finalize<<<1, 256, 0, stream>>>(gsum2, gss2, g2, be2, scale2, shift2, invN);

  // ---- layer 3 ----
  { dim3 g(256 / 16, 1); fold_w<<<g, 256, 0, stream>>>(W3, scale2, shift2, W3T, c3, 256, 128); }
  { dim3 g(MB, 1); gemm_mfma<<<g, 256, 0, stream>>>(Bb, W3T, Ab, 256, 128); }
  agg_he<<<(N_HE + 15) / 16, 256, 0, stream>>>(Ab, he_ptr, he_nodes, HEb, 128, 4, N_HE);
  agg_out<<<(N_NODES + 15) / 16, 256, 0, stream>>>(HEb, node_ptr, node_hes, b3, c3, out);
}

// Round 7
// 474.868 us; speedup vs baseline: 1.2207x; 1.1043x over previous
//
#include <hip/hip_runtime.h>

#define N_NODES 100000
#define N_HE    30000
#define N_INC   300000
#define HEPAD   30080           // 235 * 128  (GEMM M-dim padding)

typedef short  short8  __attribute__((ext_vector_type(8)));
typedef float  floatx4 __attribute__((ext_vector_type(4)));

__device__ inline unsigned short f2bf(float f) {
  unsigned int u = __float_as_uint(f);
  u = (u + 0x7fff + ((u >> 16) & 1)) >> 16;   // round-to-nearest-even
  return (unsigned short)u;
}
__device__ inline unsigned int pack2(float lo, float hi) {
  return (unsigned int)f2bf(lo) | ((unsigned int)f2bf(hi) << 16);
}
__device__ inline void acc8(uint4 rv, float* a) {
  unsigned int u;
  u = rv.x; a[0] += __uint_as_float(u << 16); a[1] += __uint_as_float(u & 0xffff0000u);
  u = rv.y; a[2] += __uint_as_float(u << 16); a[3] += __uint_as_float(u & 0xffff0000u);
  u = rv.z; a[4] += __uint_as_float(u << 16); a[5] += __uint_as_float(u & 0xffff0000u);
  u = rv.w; a[6] += __uint_as_float(u << 16); a[7] += __uint_as_float(u & 0xffff0000u);
}

// Batched segment gather: up to 4 independent row loads in flight before acc.
__device__ inline void gather4(const unsigned short* __restrict__ base,
                               const int* __restrict__ idx, int beg, int end,
                               int F, int c0, float* a) {
  for (int j = beg; j < end; j += 4) {
    int d = end - j;
    int j1 = j + (d > 1 ? 1 : 0);
    int j2 = j + (d > 2 ? 2 : 0);
    int j3 = j + (d > 3 ? 3 : 0);
    int e0 = idx[j], e1 = idx[j1], e2 = idx[j2], e3 = idx[j3];
    uint4 r0 = *(const uint4*)(base + (size_t)e0 * F + c0);
    uint4 r1 = *(const uint4*)(base + (size_t)e1 * F + c0);
    uint4 r2 = *(const uint4*)(base + (size_t)e2 * F + c0);
    uint4 r3 = *(const uint4*)(base + (size_t)e3 * F + c0);
    acc8(r0, a);
    if (d > 1) acc8(r1, a);
    if (d > 2) acc8(r2, a);
    if (d > 3) acc8(r3, a);
  }
}

// ---------------------------------------------------------------- CSR build

__global__ void zero_kernel(int* __restrict__ p, int n) {
  int i = blockIdx.x * blockDim.x + threadIdx.x;
  if (i < n) p[i] = 0;
}

__global__ void count_kernel(const int* __restrict__ nidx, const int* __restrict__ hidx,
                             int* __restrict__ node_cnt, int* __restrict__ he_cnt) {
  int i = blockIdx.x * blockDim.x + threadIdx.x;
  if (i < N_INC) {
    atomicAdd(&node_cnt[nidx[i]], 1);
    atomicAdd(&he_cnt[hidx[i]], 1);
  }
}

__global__ void scan1(const int* __restrict__ cnt, int* __restrict__ incl,
                      int* __restrict__ bsums, int n) {
  __shared__ int tmp[1024];
  int tid = threadIdx.x;
  int i = blockIdx.x * 1024 + tid;
  tmp[tid] = (i < n) ? cnt[i] : 0;
  __syncthreads();
  for (int off = 1; off < 1024; off <<= 1) {
    int t = (tid >= off) ? tmp[tid - off] : 0;
    __syncthreads();
    tmp[tid] += t;
    __syncthreads();
  }
  if (i < n) incl[i] = tmp[tid];
  if (tid == 1023) bsums[blockIdx.x] = tmp[1023];
}

__global__ void scan2(int* __restrict__ bsums, int nb) {
  if (threadIdx.x == 0 && blockIdx.x == 0) {
    int run = 0;
    for (int b = 0; b < nb; b++) { int v = bsums[b]; bsums[b] = run; run += v; }
  }
}

__global__ void scan3(const int* __restrict__ cnt, const int* __restrict__ incl,
                      const int* __restrict__ bsums, int* __restrict__ ptr,
                      int* __restrict__ fill, int n) {
  int i = blockIdx.x * 1024 + threadIdx.x;
  if (i < n) {
    int e = incl[i] - cnt[i] + bsums[blockIdx.x];
    ptr[i] = e;
    fill[i] = e;
    if (i == n - 1) ptr[n] = incl[i] + bsums[blockIdx.x];
  }
}

__global__ void fill_kernel(const int* __restrict__ nidx, const int* __restrict__ hidx,
                            int* __restrict__ node_fill, int* __restrict__ he_fill,
                            int* __restrict__ node_hes, int* __restrict__ he_nodes) {
  int i = blockIdx.x * blockDim.x + threadIdx.x;
  if (i < N_INC) {
    int nn = nidx[i], hh = hidx[i];
    int p1 = atomicAdd(&node_fill[nn], 1);
    node_hes[p1] = hh;
    int p2 = atomicAdd(&he_fill[hh], 1);
    he_nodes[p2] = nn;
  }
}

// ---------------------------------------------------------------- converters / weight fold

__global__ void convert_x(const float* __restrict__ x, unsigned short* __restrict__ xb) {
  int i = blockIdx.x * 256 + threadIdx.x;      // 8 elems per thread
  if (i >= N_NODES * 16) return;
  const float4* p = (const float4*)x + (size_t)i * 2;
  float4 a = p[0], b = p[1];
  uint4 o;
  o.x = pack2(a.x, a.y); o.y = pack2(a.z, a.w);
  o.z = pack2(b.x, b.y); o.w = pack2(b.z, b.w);
  *(uint4*)(xb + (size_t)i * 8) = o;
}

// WT[n][k] = bf16(W[k][n]*scale[k]);  cvec[n] += partial sum_k shift[k]*W[k][n]
__global__ __launch_bounds__(256) void fold_w(
    const float* __restrict__ W, const float* __restrict__ scale,
    const float* __restrict__ shift, unsigned short* __restrict__ WT,
    float* __restrict__ cvec, int K, int N) {
  int n = blockIdx.y * 256 + threadIdx.x;
  if (n >= N) return;
  int k0 = blockIdx.x * 16;
  float c = 0.f;
  unsigned short loc[16];
#pragma unroll
  for (int i = 0; i < 16; i++) {
    int k = k0 + i;
    float w = W[(size_t)k * N + n];
    float s = scale ? scale[k] : 1.f;
    float t = shift ? shift[k] : 0.f;
    loc[i] = f2bf(w * s);
    c += t * w;
  }
  *(uint4*)(WT + (size_t)n * K + k0)     = *(const uint4*)&loc[0];
  *(uint4*)(WT + (size_t)n * K + k0 + 8) = *(const uint4*)&loc[8];
  atomicAdd(cvec + n, c);
}

__global__ void bn_finalize(const float* __restrict__ gsum, const float* __restrict__ gss,
                            const float* __restrict__ g, const float* __restrict__ be,
                            float* __restrict__ scale, float* __restrict__ shift, float invN) {
  int c = threadIdx.x;  // 256
  float m = gsum[c] * invN;
  float v = gss[c] * invN - m * m;
  float sc = g[c] * rsqrtf(v + 1e-5f);
  scale[c] = sc;
  shift[c] = be[c] - m * sc;
}

// ---------------------------------------------------------------- bf16 MFMA GEMM (m97 pattern)
// C[M,N] = A[M,K] @ BT[N,K]^T. M = HEPAD (30080), grid.x = 235.

__global__ __launch_bounds__(256) void gemm_mfma(
    const unsigned short* __restrict__ A, const unsigned short* __restrict__ BT,
    unsigned short* __restrict__ C, int K, int N) {
  __shared__ unsigned short As[128 * 32];
  __shared__ unsigned short Bs[128 * 32];
  const int tid  = threadIdx.x;
  const int w    = tid >> 6, lane = tid & 63;
  const int wm   = w & 1,  wn   = w >> 1;
  const int bm   = blockIdx.x * 128, bn = blockIdx.y * 128;
  const int quad = lane >> 4, r16 = lane & 15;

  floatx4 acc[4][4] = {};

  const int srow = (lane >> 2);
  const int scol = (lane & 3) * 8;

  for (int kb = 0; kb < K; kb += 32) {
#pragma unroll
    for (int i = 0; i < 2; i++) {
      const int row = (w * 2 + i) * 16 + srow;
      const unsigned short* ga = A  + (size_t)(bm + row) * K + kb + scol;
      const unsigned short* gb = BT + (size_t)(bn + row) * K + kb + scol;
      __builtin_amdgcn_global_load_lds(
          (const __attribute__((address_space(1))) void*)ga,
          (__attribute__((address_space(3))) void*)(&As[(w * 2 + i) * 512]), 16, 0, 0);
      __builtin_amdgcn_global_load_lds(
          (const __attribute__((address_space(1))) void*)gb,
          (__attribute__((address_space(3))) void*)(&Bs[(w * 2 + i) * 512]), 16, 0, 0);
    }
    __syncthreads();
    short8 af[4], bfr[4];
#pragma unroll
    for (int t = 0; t < 4; t++) {
      af[t]  = *(const short8*)&As[(wm * 64 + t * 16 + r16) * 32 + quad * 8];
      bfr[t] = *(const short8*)&Bs[(wn * 64 + t * 16 + r16) * 32 + quad * 8];
    }
#pragma unroll
    for (int mi = 0; mi < 4; mi++)
#pragma unroll
      for (int ni = 0; ni < 4; ni++)
        acc[mi][ni] = __builtin_amdgcn_mfma_f32_16x16x32_bf16(af[mi], bfr[ni], acc[mi][ni], 0, 0, 0);
    __syncthreads();
  }
#pragma unroll
  for (int mi = 0; mi < 4; mi++)
#pragma unroll
    for (int ni = 0; ni < 4; ni++)
#pragma unroll
      for (int rr = 0; rr < 4; rr++) {
        int gm = bm + wm * 64 + mi * 16 + quad * 4 + rr;
        int gn = bn + wn * 64 + ni * 16 + r16;
        C[(size_t)gm * N + gn] = f2bf(acc[mi][ni][rr]);
      }
}

// ---------------------------------------------------------------- aggregations (bf16 in/out)

// node -> hyperedge mean over INPUT features. F/8 lanes per segment; shift=log2(F/8).
__global__ __launch_bounds__(256) void agg_he(
    const unsigned short* __restrict__ src, const int* __restrict__ ptr,
    const int* __restrict__ idx, unsigned short* __restrict__ dst,
    int F, int shift, int nSeg) {
  int seg = blockIdx.x * (256 >> shift) + (threadIdx.x >> shift);
  if (seg >= nSeg) return;
  int l = threadIdx.x & ((1 << shift) - 1);
  int c0 = l * 8;
  int beg = ptr[seg], end = ptr[seg + 1];
  float a[8] = {};
  gather4(src, idx, beg, end, F, c0, a);
  float inv = (end > beg) ? 1.0f / (float)(end - beg) : 0.0f;
  uint4 o;
  o.x = pack2(a[0] * inv, a[1] * inv);
  o.y = pack2(a[2] * inv, a[3] * inv);
  o.z = pack2(a[4] * inv, a[5] * inv);
  o.w = pack2(a[6] * inv, a[7] * inv);
  *(uint4*)(dst + (size_t)seg * F + c0) = o;
}

// hyperedge -> node, F=256: gather4 + bias(+cvec if deg>0) + relu + fused BN stats.
// 64 nodes/block (8 groups of 32 lanes x 8 nodes), grid 1563.
__global__ __launch_bounds__(256) void node_agg_bn(
    const unsigned short* __restrict__ he, const int* __restrict__ nptr,
    const int* __restrict__ nhes, const float* __restrict__ b,
    const float* __restrict__ cvec, unsigned short* __restrict__ dst,
    float* __restrict__ gsum, float* __restrict__ gss) {
  const int F = 256;
  const int grp = threadIdx.x >> 5, l = threadIdx.x & 31, c0 = l * 8;
  float bb[8], cc[8];
#pragma unroll
  for (int j = 0; j < 8; j++) { bb[j] = b[c0 + j]; cc[j] = cvec[c0 + j]; }
  float s[8] = {}, ss[8] = {};
  for (int i = 0; i < 8; i++) {
    int n = blockIdx.x * 64 + i * 8 + grp;
    if (n >= N_NODES) continue;
    int beg = nptr[n], end = nptr[n + 1];
    float a[8] = {};
    gather4(he, nhes, beg, end, F, c0, a);
    float inv = (end > beg) ? 1.0f / (float)(end - beg) : 0.0f;
    float cmul = (end > beg) ? 1.0f : 0.0f;   // deg-0 node: +b only
    float o[8];
#pragma unroll
    for (int j = 0; j < 8; j++) {
      o[j] = fmaxf(fmaf(a[j], inv, bb[j] + cmul * cc[j]), 0.f);
      s[j] += o[j]; ss[j] += o[j] * o[j];
    }
    uint4 ov;
    ov.x = pack2(o[0], o[1]); ov.y = pack2(o[2], o[3]);
    ov.z = pack2(o[4], o[5]); ov.w = pack2(o[6], o[7]);
    *(uint4*)(dst + (size_t)n * F + c0) = ov;
  }
  __shared__ float Ls[8][256];
  __shared__ float Lss[8][256];
#pragma unroll
  for (int j = 0; j < 8; j++) { Ls[grp][c0 + j] = s[j]; Lss[grp][c0 + j] = ss[j]; }
  __syncthreads();
  int c = threadIdx.x;
  float a1 = 0.f, a2 = 0.f;
#pragma unroll
  for (int h = 0; h < 8; h++) { a1 += Ls[h][c]; a2 += Lss[h][c]; }
  atomicAdd(gsum + c, a1);
  atomicAdd(gss + c, a2);
}

// final hyperedge -> node, F=128, +b3(+c3 if deg>0), relu, f32 out. 4-deep batched.
__global__ __launch_bounds__(256) void agg_out(
    const unsigned short* __restrict__ he, const int* __restrict__ nptr,
    const int* __restrict__ nhes, const float* __restrict__ b,
    const float* __restrict__ cvec, float* __restrict__ out) {
  const int F = 128;
  int g = threadIdx.x >> 4, l = threadIdx.x & 15, c0 = l * 8;
  int n = blockIdx.x * 16 + g;
  if (n >= N_NODES) return;
  int beg = nptr[n], end = nptr[n + 1];
  float a[8] = {};
  gather4(he, nhes, beg, end, F, c0, a);
  float inv = (end > beg) ? 1.0f / (float)(end - beg) : 0.0f;
  float cmul = (end > beg) ? 1.0f : 0.0f;
  float4 o0, o1;
  o0.x = fmaxf(fmaf(a[0], inv, b[c0 + 0] + cmul * cvec[c0 + 0]), 0.f);
  o0.y = fmaxf(fmaf(a[1], inv, b[c0 + 1] + cmul * cvec[c0 + 1]), 0.f);
  o0.z = fmaxf(fmaf(a[2], inv, b[c0 + 2] + cmul * cvec[c0 + 2]), 0.f);
  o0.w = fmaxf(fmaf(a[3], inv, b[c0 + 3] + cmul * cvec[c0 + 3]), 0.f);
  o1.x = fmaxf(fmaf(a[4], inv, b[c0 + 4] + cmul * cvec[c0 + 4]), 0.f);
  o1.y = fmaxf(fmaf(a[5], inv, b[c0 + 5] + cmul * cvec[c0 + 5]), 0.f);
  o1.z = fmaxf(fmaf(a[6], inv, b[c0 + 6] + cmul * cvec[c0 + 6]), 0.f);
  o1.w = fmaxf(fmaf(a[7], inv, b[c0 + 7] + cmul * cvec[c0 + 7]), 0.f);
  float* dp = out + (size_t)n * F + c0;
  *(float4*)dp = o0;
  *(float4*)(dp + 4) = o1;
}

// ---------------------------------------------------------------- launch

extern "C" void kernel_launch(void* const* d_in, const int* in_sizes, int n_in,
                              void* d_out, int out_size, void* d_ws, size_t ws_size,
                              hipStream_t stream) {
  const float* x    = (const float*)d_in[0];
  const int*   edge = (const int*)d_in[1];
  const int*   nidx = edge;
  const int*   hidx = edge + N_INC;
  const float* W1  = (const float*)d_in[2];
  const float* b1  = (const float*)d_in[3];
  const float* g1  = (const float*)d_in[4];
  const float* be1 = (const float*)d_in[5];
  const float* W2  = (const float*)d_in[6];
  const float* b2  = (const float*)d_in[7];
  const float* g2  = (const float*)d_in[8];
  const float* be2 = (const float*)d_in[9];
  const float* W3  = (const float*)d_in[10];
  const float* b3  = (const float*)d_in[11];
  float* out = (float*)d_out;

  char* ws = (char*)d_ws;
  size_t off = 0;
  auto alloc = [&](size_t bytes) -> void* {
    void* p = ws + off;
    off = (off + bytes + 255) & ~(size_t)255;
    return p;
  };
  unsigned short* Xb   = (unsigned short*)alloc((size_t)N_NODES * 128 * 2);
  unsigned short* Bb   = (unsigned short*)alloc((size_t)N_NODES * 256 * 2);
  unsigned short* Hraw = (unsigned short*)alloc((size_t)HEPAD * 256 * 2);
  unsigned short* HEb  = (unsigned short*)alloc((size_t)HEPAD * 256 * 2);
  unsigned short* W1T  = (unsigned short*)alloc((size_t)256 * 128 * 2);
  unsigned short* W2T  = (unsigned short*)alloc((size_t)256 * 256 * 2);
  unsigned short* W3T  = (unsigned short*)alloc((size_t)128 * 256 * 2);
  size_t zero_begin = off;
  int* he_cnt   = (int*)alloc((size_t)N_HE * 4);
  int* node_cnt = (int*)alloc((size_t)N_NODES * 4);
  float* gsum1 = (float*)alloc(1024);
  float* gss1  = (float*)alloc(1024);
  float* gsum2 = (float*)alloc(1024);
  float* gss2  = (float*)alloc(1024);
  float* c1 = (float*)alloc(1024);
  float* c2 = (float*)alloc(1024);
  float* c3 = (float*)alloc(1024);
  size_t zero_end = off;
  int* he_ptr    = (int*)alloc((size_t)(N_HE + 1) * 4);
  int* node_ptr  = (int*)alloc((size_t)(N_NODES + 1) * 4);
  int* he_fill   = (int*)alloc((size_t)N_HE * 4);
  int* node_fill = (int*)alloc((size_t)N_NODES * 4);
  int* he_nodes  = (int*)alloc((size_t)N_INC * 4);
  int* node_hes  = (int*)alloc((size_t)N_INC * 4);
  int* incl      = (int*)alloc((size_t)N_NODES * 4);
  int* bsums     = (int*)alloc(512);
  float* scale1 = (float*)alloc(1024);
  float* shift1 = (float*)alloc(1024);
  float* scale2 = (float*)alloc(1024);
  float* shift2 = (float*)alloc(1024);

  // ---- CSR build ----
  int zero_ints = (int)((zero_end - zero_begin) / 4);
  zero_kernel<<<(zero_ints + 255) / 256, 256, 0, stream>>>(he_cnt, zero_ints);
  count_kernel<<<(N_INC + 255) / 256, 256, 0, stream>>>(nidx, hidx, node_cnt, he_cnt);
  {
    int nb = (N_HE + 1023) / 1024;
    scan1<<<nb, 1024, 0, stream>>>(he_cnt, incl, bsums, N_HE);
    scan2<<<1, 64, 0, stream>>>(bsums, nb);
    scan3<<<nb, 1024, 0, stream>>>(he_cnt, incl, bsums, he_ptr, he_fill, N_HE);
  }
  {
    int nb = (N_NODES + 1023) / 1024;
    scan1<<<nb, 1024, 0, stream>>>(node_cnt, incl, bsums, N_NODES);
    scan2<<<1, 64, 0, stream>>>(bsums, nb);
    scan3<<<nb, 1024, 0, stream>>>(node_cnt, incl, bsums, node_ptr, node_fill, N_NODES);
  }
  fill_kernel<<<(N_INC + 255) / 256, 256, 0, stream>>>(nidx, hidx, node_fill, he_fill,
                                                       node_hes, he_nodes);

  // ---- precompute ----
  convert_x<<<(N_NODES * 16 + 255) / 256, 256, 0, stream>>>(x, Xb);
  { dim3 g(128 / 16, 1); fold_w<<<g, 256, 0, stream>>>(W1, nullptr, nullptr, W1T, c1, 128, 256); }

  const int MBHE = HEPAD / 128;         // 235
  const float invN = 1.0f / (float)N_NODES;

  // ---- layer 1: He_raw = agg_he(x) [30k x 128]; HE = He_raw @ W1 [30k x 256] ----
  agg_he<<<(N_HE + 15) / 16, 256, 0, stream>>>(Xb, he_ptr, he_nodes, Hraw, 128, 4, N_HE);
  { dim3 g(MBHE, 2); gemm_mfma<<<g, 256, 0, stream>>>(Hraw, W1T, HEb, 128, 256); }
  node_agg_bn<<<(N_NODES + 63) / 64, 256, 0, stream>>>(HEb, node_ptr, node_hes, b1, c1,
                                                       Bb, gsum1, gss1);
  bn_finalize<<<1, 256, 0, stream>>>(gsum1, gss1, g1, be1, scale1, shift1, invN);

  // ---- layer 2 ----
  { dim3 g(256 / 16, 1); fold_w<<<g, 256, 0, stream>>>(W2, scale1, shift1, W2T, c2, 256, 256); }
  agg_he<<<(N_HE + 7) / 8, 256, 0, stream>>>(Bb, he_ptr, he_nodes, Hraw, 256, 5, N_HE);
  { dim3 g(MBHE, 2); gemm_mfma<<<g, 256, 0, stream>>>(Hraw, W2T, HEb, 256, 256); }
  node_agg_bn<<<(N_NODES + 63) / 64, 256, 0, stream>>>(HEb, node_ptr, node_hes, b2, c2,
                                                       Bb, gsum2, gss2);
  bn_finalize<<<1, 256, 0, stream>>>(gsum2, gss2, g2, be2, scale2, shift2, invN);

  // ---- layer 3: He_raw = agg_he(Bb) [30k x 256]; HE = He_raw @ W3 [30k x 128] ----
  { dim3 g(256 / 16, 1); fold_w<<<g, 256, 0, stream>>>(W3, scale2, shift2, W3T, c3, 256, 128); }
  agg_he<<<(N_HE + 7) / 8, 256, 0, stream>>>(Bb, he_ptr, he_nodes, Hraw, 256, 5, N_HE);
  { dim3 g(MBHE, 1); gemm_mfma<<<g, 256, 0, stream>>>(Hraw, W3T, HEb, 256, 128); }
  agg_out<<<(N_NODES + 15) / 16, 256, 0, stream>>>(HEb, node_ptr, node_hes, b3, c3, out);
}

// Round 8
// 450.815 us; speedup vs baseline: 1.2859x; 1.0534x over previous
//
#include <hip/hip_runtime.h>

#define N_NODES 100000
#define N_HE    30000
#define N_INC   300000
#define HEPAD   30080           // 235 * 128  (GEMM M-dim padding)

typedef short  short8  __attribute__((ext_vector_type(8)));
typedef float  floatx4 __attribute__((ext_vector_type(4)));

__device__ inline unsigned short f2bf(float f) {
  unsigned int u = __float_as_uint(f);
  u = (u + 0x7fff + ((u >> 16) & 1)) >> 16;   // round-to-nearest-even
  return (unsigned short)u;
}
__device__ inline unsigned int pack2(float lo, float hi) {
  return (unsigned int)f2bf(lo) | ((unsigned int)f2bf(hi) << 16);
}
__device__ inline void acc8(uint4 rv, float* a) {
  unsigned int u;
  u = rv.x; a[0] += __uint_as_float(u << 16); a[1] += __uint_as_float(u & 0xffff0000u);
  u = rv.y; a[2] += __uint_as_float(u << 16); a[3] += __uint_as_float(u & 0xffff0000u);
  u = rv.z; a[4] += __uint_as_float(u << 16); a[5] += __uint_as_float(u & 0xffff0000u);
  u = rv.w; a[6] += __uint_as_float(u << 16); a[7] += __uint_as_float(u & 0xffff0000u);
}

struct R8 { uint4 r[8]; };

__device__ inline void load8(const unsigned short* __restrict__ base, const int* e,
                             int F, int c0, R8& o) {
#pragma unroll
  for (int k = 0; k < 8; k++)
    o.r[k] = *(const uint4*)(base + (size_t)e[k] * F + c0);
}
__device__ inline void accm8(const R8& o, int d, float* a) {
  acc8(o.r[0], a);
  if (d > 1) acc8(o.r[1], a);
  if (d > 2) acc8(o.r[2], a);
  if (d > 3) acc8(o.r[3], a);
  if (d > 4) acc8(o.r[4], a);
  if (d > 5) acc8(o.r[5], a);
  if (d > 6) acc8(o.r[6], a);
  if (d > 7) acc8(o.r[7], a);
}

// Pipelined 8-deep segment gather: rows for batch j in flight while idx for
// batch j+1 is prefetched. Clamped idx -> duplicate loads are L1 hits.
__device__ inline void gather8p(const unsigned short* __restrict__ base,
                                const int* __restrict__ idx, int beg, int end,
                                int F, int c0, float* a) {
  if (beg >= end) return;
  int e[8];
#pragma unroll
  for (int k = 0; k < 8; k++) e[k] = idx[min(beg + k, end - 1)];
  for (int j = beg; j < end; j += 8) {
    R8 r;
    load8(base, e, F, c0, r);
    int jn = j + 8;
    if (jn < end) {
#pragma unroll
      for (int k = 0; k < 8; k++) e[k] = idx[min(jn + k, end - 1)];
    }
    accm8(r, end - j, a);
  }
}

// ---------------------------------------------------------------- CSR build

__global__ void count_kernel(const int* __restrict__ nidx, const int* __restrict__ hidx,
                             int* __restrict__ node_cnt, int* __restrict__ he_cnt) {
  int i = blockIdx.x * blockDim.x + threadIdx.x;
  if (i < N_INC) {
    atomicAdd(&node_cnt[nidx[i]], 1);
    atomicAdd(&he_cnt[hidx[i]], 1);
  }
}

__global__ void scan1(const int* __restrict__ cnt, int* __restrict__ incl,
                      int* __restrict__ bsums, int n) {
  __shared__ int tmp[1024];
  int tid = threadIdx.x;
  int i = blockIdx.x * 1024 + tid;
  tmp[tid] = (i < n) ? cnt[i] : 0;
  __syncthreads();
  for (int off = 1; off < 1024; off <<= 1) {
    int t = (tid >= off) ? tmp[tid - off] : 0;
    __syncthreads();
    tmp[tid] += t;
    __syncthreads();
  }
  if (i < n) incl[i] = tmp[tid];
  if (tid == 1023) bsums[blockIdx.x] = tmp[1023];
}

__global__ void scan2(int* __restrict__ bsums, int nb) {
  if (threadIdx.x == 0 && blockIdx.x == 0) {
    int run = 0;
    for (int b = 0; b < nb; b++) { int v = bsums[b]; bsums[b] = run; run += v; }
  }
}

__global__ void scan3(const int* __restrict__ cnt, const int* __restrict__ incl,
                      const int* __restrict__ bsums, int* __restrict__ ptr,
                      int* __restrict__ fill, int n) {
  int i = blockIdx.x * 1024 + threadIdx.x;
  if (i < n) {
    int e = incl[i] - cnt[i] + bsums[blockIdx.x];
    ptr[i] = e;
    fill[i] = e;
    if (i == n - 1) ptr[n] = incl[i] + bsums[blockIdx.x];
  }
}

__global__ void fill_kernel(const int* __restrict__ nidx, const int* __restrict__ hidx,
                            int* __restrict__ node_fill, int* __restrict__ he_fill,
                            int* __restrict__ node_hes, int* __restrict__ he_nodes) {
  int i = blockIdx.x * blockDim.x + threadIdx.x;
  if (i < N_INC) {
    int nn = nidx[i], hh = hidx[i];
    int p1 = atomicAdd(&node_fill[nn], 1);
    node_hes[p1] = hh;
    int p2 = atomicAdd(&he_fill[hh], 1);
    he_nodes[p2] = nn;
  }
}

// ---------------------------------------------------------------- converters / weight fold

__global__ void convert_x(const float* __restrict__ x, unsigned short* __restrict__ xb) {
  int i = blockIdx.x * 256 + threadIdx.x;      // 8 elems per thread
  if (i >= N_NODES * 16) return;
  const float4* p = (const float4*)x + (size_t)i * 2;
  float4 a = p[0], b = p[1];
  uint4 o;
  o.x = pack2(a.x, a.y); o.y = pack2(a.z, a.w);
  o.z = pack2(b.x, b.y); o.w = pack2(b.z, b.w);
  *(uint4*)(xb + (size_t)i * 8) = o;
}

// Fused BN-finalize + weight fold:
//   scale[k] = g[k]*rsqrt(var_k+eps), shift[k] = be[k]-mean_k*scale[k]
//   WT[n][k] = bf16(W[k][n]*scale[k]); cvec[n] += sum_k shift[k]*W[k][n]
// gsum==nullptr -> identity (layer 1). cvec must be pre-zeroed.
__global__ __launch_bounds__(256) void fold_w(
    const float* __restrict__ W, const float* __restrict__ gsum,
    const float* __restrict__ gss, const float* __restrict__ g,
    const float* __restrict__ be, unsigned short* __restrict__ WT,
    float* __restrict__ cvec, int K, int N, float invN) {
  int n = blockIdx.y * 256 + threadIdx.x;
  if (n >= N) return;
  int k0 = blockIdx.x * 16;
  float c = 0.f;
  unsigned short loc[16];
#pragma unroll
  for (int i = 0; i < 16; i++) {
    int k = k0 + i;
    float w = W[(size_t)k * N + n];
    float s = 1.f, t = 0.f;
    if (gsum) {
      float m = gsum[k] * invN;
      float v = gss[k] * invN - m * m;
      s = g[k] * rsqrtf(v + 1e-5f);
      t = be[k] - m * s;
    }
    loc[i] = f2bf(w * s);
    c += t * w;
  }
  *(uint4*)(WT + (size_t)n * K + k0)     = *(const uint4*)&loc[0];
  *(uint4*)(WT + (size_t)n * K + k0 + 8) = *(const uint4*)&loc[8];
  atomicAdd(cvec + n, c);
}

// ---------------------------------------------------------------- bf16 MFMA GEMM (m97 pattern)
// C[M,N] = A[M,K] @ BT[N,K]^T. M = HEPAD (30080), grid.x = 235.

__global__ __launch_bounds__(256) void gemm_mfma(
    const unsigned short* __restrict__ A, const unsigned short* __restrict__ BT,
    unsigned short* __restrict__ C, int K, int N) {
  __shared__ unsigned short As[128 * 32];
  __shared__ unsigned short Bs[128 * 32];
  const int tid  = threadIdx.x;
  const int w    = tid >> 6, lane = tid & 63;
  const int wm   = w & 1,  wn   = w >> 1;
  const int bm   = blockIdx.x * 128, bn = blockIdx.y * 128;
  const int quad = lane >> 4, r16 = lane & 15;

  floatx4 acc[4][4] = {};

  const int srow = (lane >> 2);
  const int scol = (lane & 3) * 8;

  for (int kb = 0; kb < K; kb += 32) {
#pragma unroll
    for (int i = 0; i < 2; i++) {
      const int row = (w * 2 + i) * 16 + srow;
      const unsigned short* ga = A  + (size_t)(bm + row) * K + kb + scol;
      const unsigned short* gb = BT + (size_t)(bn + row) * K + kb + scol;
      __builtin_amdgcn_global_load_lds(
          (const __attribute__((address_space(1))) void*)ga,
          (__attribute__((address_space(3))) void*)(&As[(w * 2 + i) * 512]), 16, 0, 0);
      __builtin_amdgcn_global_load_lds(
          (const __attribute__((address_space(1))) void*)gb,
          (__attribute__((address_space(3))) void*)(&Bs[(w * 2 + i) * 512]), 16, 0, 0);
    }
    __syncthreads();
    short8 af[4], bfr[4];
#pragma unroll
    for (int t = 0; t < 4; t++) {
      af[t]  = *(const short8*)&As[(wm * 64 + t * 16 + r16) * 32 + quad * 8];
      bfr[t] = *(const short8*)&Bs[(wn * 64 + t * 16 + r16) * 32 + quad * 8];
    }
#pragma unroll
    for (int mi = 0; mi < 4; mi++)
#pragma unroll
      for (int ni = 0; ni < 4; ni++)
        acc[mi][ni] = __builtin_amdgcn_mfma_f32_16x16x32_bf16(af[mi], bfr[ni], acc[mi][ni], 0, 0, 0);
    __syncthreads();
  }
#pragma unroll
  for (int mi = 0; mi < 4; mi++)
#pragma unroll
    for (int ni = 0; ni < 4; ni++)
#pragma unroll
      for (int rr = 0; rr < 4; rr++) {
        int gm = bm + wm * 64 + mi * 16 + quad * 4 + rr;
        int gn = bn + wn * 64 + ni * 16 + r16;
        C[(size_t)gm * N + gn] = f2bf(acc[mi][ni][rr]);
      }
}

// ---------------------------------------------------------------- aggregations (bf16 in/out)

// node -> hyperedge mean over input features. F/8 lanes per segment; shift=log2(F/8).
__global__ __launch_bounds__(256) void agg_he(
    const unsigned short* __restrict__ src, const int* __restrict__ ptr,
    const int* __restrict__ idx, unsigned short* __restrict__ dst,
    int F, int shift, int nSeg) {
  int seg = blockIdx.x * (256 >> shift) + (threadIdx.x >> shift);
  if (seg >= nSeg) return;
  int l = threadIdx.x & ((1 << shift) - 1);
  int c0 = l * 8;
  int beg = ptr[seg], end = ptr[seg + 1];
  float a[8] = {};
  gather8p(src, idx, beg, end, F, c0, a);
  float inv = (end > beg) ? 1.0f / (float)(end - beg) : 0.0f;
  uint4 o;
  o.x = pack2(a[0] * inv, a[1] * inv);
  o.y = pack2(a[2] * inv, a[3] * inv);
  o.z = pack2(a[4] * inv, a[5] * inv);
  o.w = pack2(a[6] * inv, a[7] * inv);
  *(uint4*)(dst + (size_t)seg * F + c0) = o;
}

// hyperedge -> node, F=256: software-pipelined gather + bias(+cvec) + relu + BN stats.
// 64 nodes/block (8 groups of 32 lanes x 8 nodes). Bounds preloaded; idx for node
// i+1 prefetched while node i's row loads are in flight.
__global__ __launch_bounds__(256) void node_agg_bn(
    const unsigned short* __restrict__ he, const int* __restrict__ nptr,
    const int* __restrict__ nhes, const float* __restrict__ b,
    const float* __restrict__ cvec, unsigned short* __restrict__ dst,
    float* __restrict__ gsum, float* __restrict__ gss) {
  const int F = 256;
  const int grp = threadIdx.x >> 5, l = threadIdx.x & 31, c0 = l * 8;
  float bb[8], cc[8];
#pragma unroll
  for (int j = 0; j < 8; j++) { bb[j] = b[c0 + j]; cc[j] = cvec[c0 + j]; }
  // preload bounds for this group's 8 nodes (16 independent loads)
  int begs[8], ends[8];
#pragma unroll
  for (int i = 0; i < 8; i++) {
    int n = blockIdx.x * 64 + i * 8 + grp;
    begs[i] = (n < N_NODES) ? nptr[n] : 0;
    ends[i] = (n < N_NODES) ? nptr[n + 1] : 0;
  }
  float s[8] = {}, ss[8] = {};
  // prefetch idx batch for node 0
  int e[8];
#pragma unroll
  for (int k = 0; k < 8; k++)
    e[k] = (begs[0] < ends[0]) ? nhes[min(begs[0] + k, ends[0] - 1)] : 0;
  for (int i = 0; i < 8; i++) {
    const int beg = begs[i], end = ends[i];
    const int d = end - beg;
    const int n = blockIdx.x * 64 + i * 8 + grp;
    float a[8] = {};
    R8 r;
    if (d > 0) load8(he, e, F, c0, r);          // rows in flight...
    if (i < 7) {                                 // ...while next idx prefetches
      int bn2 = begs[i + 1], en2 = ends[i + 1];
#pragma unroll
      for (int k = 0; k < 8; k++)
        e[k] = (bn2 < en2) ? nhes[min(bn2 + k, en2 - 1)] : 0;
    }
    if (d > 0) {
      accm8(r, d, a);
      for (int j = beg + 8; j < end; j += 8) {   // rare tail (deg > 8)
        int et[8];
#pragma unroll
        for (int k = 0; k < 8; k++) et[k] = nhes[min(j + k, end - 1)];
        R8 t;
        load8(he, et, F, c0, t);
        accm8(t, end - j, a);
      }
    }
    if (n < N_NODES) {
      float inv  = (d > 0) ? 1.0f / (float)d : 0.0f;
      float cmul = (d > 0) ? 1.0f : 0.0f;        // deg-0 node: +b only
      float o[8];
#pragma unroll
      for (int j = 0; j < 8; j++) {
        o[j] = fmaxf(fmaf(a[j], inv, bb[j] + cmul * cc[j]), 0.f);
        s[j] += o[j]; ss[j] += o[j] * o[j];
      }
      uint4 ov;
      ov.x = pack2(o[0], o[1]); ov.y = pack2(o[2], o[3]);
      ov.z = pack2(o[4], o[5]); ov.w = pack2(o[6], o[7]);
      *(uint4*)(dst + (size_t)n * F + c0) = ov;
    }
  }
  __shared__ float Ls[8][256];
  __shared__ float Lss[8][256];
#pragma unroll
  for (int j = 0; j < 8; j++) { Ls[grp][c0 + j] = s[j]; Lss[grp][c0 + j] = ss[j]; }
  __syncthreads();
  int c = threadIdx.x;
  float a1 = 0.f, a2 = 0.f;
#pragma unroll
  for (int h = 0; h < 8; h++) { a1 += Ls[h][c]; a2 += Lss[h][c]; }
  atomicAdd(gsum + c, a1);
  atomicAdd(gss + c, a2);
}

// final hyperedge -> node, F=128, +b3(+c3 if deg>0), relu, f32 out.
__global__ __launch_bounds__(256) void agg_out(
    const unsigned short* __restrict__ he, const int* __restrict__ nptr,
    const int* __restrict__ nhes, const float* __restrict__ b,
    const float* __restrict__ cvec, float* __restrict__ out) {
  const int F = 128;
  int g = threadIdx.x >> 4, l = threadIdx.x & 15, c0 = l * 8;
  int n = blockIdx.x * 16 + g;
  if (n >= N_NODES) return;
  int beg = nptr[n], end = nptr[n + 1];
  float a[8] = {};
  gather8p(he, nhes, beg, end, F, c0, a);
  float inv = (end > beg) ? 1.0f / (float)(end - beg) : 0.0f;
  float cmul = (end > beg) ? 1.0f : 0.0f;
  float4 o0, o1;
  o0.x = fmaxf(fmaf(a[0], inv, b[c0 + 0] + cmul * cvec[c0 + 0]), 0.f);
  o0.y = fmaxf(fmaf(a[1], inv, b[c0 + 1] + cmul * cvec[c0 + 1]), 0.f);
  o0.z = fmaxf(fmaf(a[2], inv, b[c0 + 2] + cmul * cvec[c0 + 2]), 0.f);
  o0.w = fmaxf(fmaf(a[3], inv, b[c0 + 3] + cmul * cvec[c0 + 3]), 0.f);
  o1.x = fmaxf(fmaf(a[4], inv, b[c0 + 4] + cmul * cvec[c0 + 4]), 0.f);
  o1.y = fmaxf(fmaf(a[5], inv, b[c0 + 5] + cmul * cvec[c0 + 5]), 0.f);
  o1.z = fmaxf(fmaf(a[6], inv, b[c0 + 6] + cmul * cvec[c0 + 6]), 0.f);
  o1.w = fmaxf(fmaf(a[7], inv, b[c0 + 7] + cmul * cvec[c0 + 7]), 0.f);
  float* dp = out + (size_t)n * F + c0;
  *(float4*)dp = o0;
  *(float4*)(dp + 4) = o1;
}

// ---------------------------------------------------------------- launch

extern "C" void kernel_launch(void* const* d_in, const int* in_sizes, int n_in,
                              void* d_out, int out_size, void* d_ws, size_t ws_size,
                              hipStream_t stream) {
  const float* x    = (const float*)d_in[0];
  const int*   edge = (const int*)d_in[1];
  const int*   nidx = edge;
  const int*   hidx = edge + N_INC;
  const float* W1  = (const float*)d_in[2];
  const float* b1  = (const float*)d_in[3];
  const float* g1  = (const float*)d_in[4];
  const float* be1 = (const float*)d_in[5];
  const float* W2  = (const float*)d_in[6];
  const float* b2  = (const float*)d_in[7];
  const float* g2  = (const float*)d_in[8];
  const float* be2 = (const float*)d_in[9];
  const float* W3  = (const float*)d_in[10];
  const float* b3  = (const float*)d_in[11];
  float* out = (float*)d_out;

  char* ws = (char*)d_ws;
  size_t off = 0;
  auto alloc = [&](size_t bytes) -> void* {
    void* p = ws + off;
    off = (off + bytes + 255) & ~(size_t)255;
    return p;
  };
  unsigned short* Xb   = (unsigned short*)alloc((size_t)N_NODES * 128 * 2);
  unsigned short* Bb   = (unsigned short*)alloc((size_t)N_NODES * 256 * 2);
  unsigned short* Hraw = (unsigned short*)alloc((size_t)HEPAD * 256 * 2);
  unsigned short* HEb  = (unsigned short*)alloc((size_t)HEPAD * 256 * 2);
  unsigned short* W1T  = (unsigned short*)alloc((size_t)256 * 128 * 2);
  unsigned short* W2T  = (unsigned short*)alloc((size_t)256 * 256 * 2);
  unsigned short* W3T  = (unsigned short*)alloc((size_t)128 * 256 * 2);
  size_t zero_begin = off;
  int* he_cnt   = (int*)alloc((size_t)N_HE * 4);
  int* node_cnt = (int*)alloc((size_t)N_NODES * 4);
  float* gsum1 = (float*)alloc(1024);
  float* gss1  = (float*)alloc(1024);
  float* gsum2 = (float*)alloc(1024);
  float* gss2  = (float*)alloc(1024);
  float* c1 = (float*)alloc(1024);
  float* c2 = (float*)alloc(1024);
  float* c3 = (float*)alloc(1024);
  size_t zero_end = off;
  int* he_ptr    = (int*)alloc((size_t)(N_HE + 1) * 4);
  int* node_ptr  = (int*)alloc((size_t)(N_NODES + 1) * 4);
  int* he_fill   = (int*)alloc((size_t)N_HE * 4);
  int* node_fill = (int*)alloc((size_t)N_NODES * 4);
  int* he_nodes  = (int*)alloc((size_t)N_INC * 4);
  int* node_hes  = (int*)alloc((size_t)N_INC * 4);
  int* incl      = (int*)alloc((size_t)N_NODES * 4);
  int* bsums     = (int*)alloc(512);

  // ---- zero counters/accumulators (single async memset) ----
  hipMemsetAsync((void*)(ws + zero_begin), 0, zero_end - zero_begin, stream);

  // ---- CSR build ----
  count_kernel<<<(N_INC + 255) / 256, 256, 0, stream>>>(nidx, hidx, node_cnt, he_cnt);
  {
    int nb = (N_HE + 1023) / 1024;
    scan1<<<nb, 1024, 0, stream>>>(he_cnt, incl, bsums, N_HE);
    scan2<<<1, 64, 0, stream>>>(bsums, nb);
    scan3<<<nb, 1024, 0, stream>>>(he_cnt, incl, bsums, he_ptr, he_fill, N_HE);
  }
  {
    int nb = (N_NODES + 1023) / 1024;
    scan1<<<nb, 1024, 0, stream>>>(node_cnt, incl, bsums, N_NODES);
    scan2<<<1, 64, 0, stream>>>(bsums, nb);
    scan3<<<nb, 1024, 0, stream>>>(node_cnt, incl, bsums, node_ptr, node_fill, N_NODES);
  }
  fill_kernel<<<(N_INC + 255) / 256, 256, 0, stream>>>(nidx, hidx, node_fill, he_fill,
                                                       node_hes, he_nodes);

  // ---- precompute ----
  convert_x<<<(N_NODES * 16 + 255) / 256, 256, 0, stream>>>(x, Xb);
  { dim3 g(128 / 16, 1);
    fold_w<<<g, 256, 0, stream>>>(W1, nullptr, nullptr, nullptr, nullptr, W1T, c1, 128, 256, 0.f); }

  const int MBHE = HEPAD / 128;         // 235
  const float invN = 1.0f / (float)N_NODES;

  // ---- layer 1: Hraw = agg_he(x) [30k x 128]; HEb = Hraw @ W1 [30k x 256] ----
  agg_he<<<(N_HE + 15) / 16, 256, 0, stream>>>(Xb, he_ptr, he_nodes, Hraw, 128, 4, N_HE);
  { dim3 g(MBHE, 2); gemm_mfma<<<g, 256, 0, stream>>>(Hraw, W1T, HEb, 128, 256); }
  node_agg_bn<<<(N_NODES + 63) / 64, 256, 0, stream>>>(HEb, node_ptr, node_hes, b1, c1,
                                                       Bb, gsum1, gss1);

  // ---- layer 2 ----
  { dim3 g(256 / 16, 1);
    fold_w<<<g, 256, 0, stream>>>(W2, gsum1, gss1, g1, be1, W2T, c2, 256, 256, invN); }
  agg_he<<<(N_HE + 7) / 8, 256, 0, stream>>>(Bb, he_ptr, he_nodes, Hraw, 256, 5, N_HE);
  { dim3 g(MBHE, 2); gemm_mfma<<<g, 256, 0, stream>>>(Hraw, W2T, HEb, 256, 256); }
  node_agg_bn<<<(N_NODES + 63) / 64, 256, 0, stream>>>(HEb, node_ptr, node_hes, b2, c2,
                                                       Bb, gsum2, gss2);

  // ---- layer 3 ----
  { dim3 g(256 / 16, 1);
    fold_w<<<g, 256, 0, stream>>>(W3, gsum2, gss2, g2, be2, W3T, c3, 256, 128, invN); }
  agg_he<<<(N_HE + 7) / 8, 256, 0, stream>>>(Bb, he_ptr, he_nodes, Hraw, 256, 5, N_HE);
  { dim3 g(MBHE, 1); gemm_mfma<<<g, 256, 0, stream>>>(Hraw, W3T, HEb, 256, 128); }
  agg_out<<<(N_NODES + 15) / 16, 256, 0, stream>>>(HEb, node_ptr, node_hes, b3, c3, out);
}

// Round 9
// 442.788 us; speedup vs baseline: 1.3092x; 1.0181x over previous
//
#include <hip/hip_runtime.h>

#define N_NODES 100000
#define N_HE    30000
#define N_INC   300000
#define HEPAD   30080           // 235 * 128  (GEMM M-dim padding)

typedef short  short8  __attribute__((ext_vector_type(8)));
typedef float  floatx4 __attribute__((ext_vector_type(4)));

__device__ inline unsigned short f2bf(float f) {
  unsigned int u = __float_as_uint(f);
  u = (u + 0x7fff + ((u >> 16) & 1)) >> 16;   // round-to-nearest-even
  return (unsigned short)u;
}
__device__ inline unsigned int pack2(float lo, float hi) {
  return (unsigned int)f2bf(lo) | ((unsigned int)f2bf(hi) << 16);
}
__device__ inline void acc8(uint4 rv, float* a) {
  unsigned int u;
  u = rv.x; a[0] += __uint_as_float(u << 16); a[1] += __uint_as_float(u & 0xffff0000u);
  u = rv.y; a[2] += __uint_as_float(u << 16); a[3] += __uint_as_float(u & 0xffff0000u);
  u = rv.z; a[4] += __uint_as_float(u << 16); a[5] += __uint_as_float(u & 0xffff0000u);
  u = rv.w; a[6] += __uint_as_float(u << 16); a[7] += __uint_as_float(u & 0xffff0000u);
}

struct R4 { uint4 r[4]; };
struct R8 { uint4 r[8]; };

__device__ inline void load4(const unsigned short* __restrict__ base, const int* e,
                             int F, int c0, R4& o) {
#pragma unroll
  for (int k = 0; k < 4; k++)
    o.r[k] = *(const uint4*)(base + (size_t)e[k] * F + c0);
}
__device__ inline void accm4(const R4& o, int d, float* a) {
  if (d > 0) acc8(o.r[0], a);
  if (d > 1) acc8(o.r[1], a);
  if (d > 2) acc8(o.r[2], a);
  if (d > 3) acc8(o.r[3], a);
}
__device__ inline void load8(const unsigned short* __restrict__ base, const int* e,
                             int F, int c0, R8& o) {
#pragma unroll
  for (int k = 0; k < 8; k++)
    o.r[k] = *(const uint4*)(base + (size_t)e[k] * F + c0);
}
__device__ inline void accm8(const R8& o, int d, float* a) {
  acc8(o.r[0], a);
  if (d > 1) acc8(o.r[1], a);
  if (d > 2) acc8(o.r[2], a);
  if (d > 3) acc8(o.r[3], a);
  if (d > 4) acc8(o.r[4], a);
  if (d > 5) acc8(o.r[5], a);
  if (d > 6) acc8(o.r[6], a);
  if (d > 7) acc8(o.r[7], a);
}

// Pipelined 8-deep segment gather (for deg~10 hyperedge side).
__device__ inline void gather8p(const unsigned short* __restrict__ base,
                                const int* __restrict__ idx, int beg, int end,
                                int F, int c0, float* a) {
  if (beg >= end) return;
  int e[8];
#pragma unroll
  for (int k = 0; k < 8; k++) e[k] = idx[min(beg + k, end - 1)];
  for (int j = beg; j < end; j += 8) {
    R8 r;
    load8(base, e, F, c0, r);
    int jn = j + 8;
    if (jn < end) {
#pragma unroll
      for (int k = 0; k < 8; k++) e[k] = idx[min(jn + k, end - 1)];
    }
    accm8(r, end - j, a);
  }
}

// ---------------------------------------------------------------- CSR build

__global__ void count_kernel(const int* __restrict__ nidx, const int* __restrict__ hidx,
                             int* __restrict__ node_cnt, int* __restrict__ he_cnt) {
  int i = blockIdx.x * blockDim.x + threadIdx.x;
  if (i < N_INC) {
    atomicAdd(&node_cnt[nidx[i]], 1);
    atomicAdd(&he_cnt[hidx[i]], 1);
  }
}

__global__ void scan1(const int* __restrict__ cnt, int* __restrict__ incl,
                      int* __restrict__ bsums, int n) {
  __shared__ int tmp[1024];
  int tid = threadIdx.x;
  int i = blockIdx.x * 1024 + tid;
  tmp[tid] = (i < n) ? cnt[i] : 0;
  __syncthreads();
  for (int off = 1; off < 1024; off <<= 1) {
    int t = (tid >= off) ? tmp[tid - off] : 0;
    __syncthreads();
    tmp[tid] += t;
    __syncthreads();
  }
  if (i < n) incl[i] = tmp[tid];
  if (tid == 1023) bsums[blockIdx.x] = tmp[1023];
}

__global__ void scan2(int* __restrict__ bsums, int nb) {
  if (threadIdx.x == 0 && blockIdx.x == 0) {
    int run = 0;
    for (int b = 0; b < nb; b++) { int v = bsums[b]; bsums[b] = run; run += v; }
  }
}

__global__ void scan3(const int* __restrict__ cnt, const int* __restrict__ incl,
                      const int* __restrict__ bsums, int* __restrict__ ptr,
                      int* __restrict__ fill, int n) {
  int i = blockIdx.x * 1024 + threadIdx.x;
  if (i < n) {
    int e = incl[i] - cnt[i] + bsums[blockIdx.x];
    ptr[i] = e;
    fill[i] = e;
    if (i == n - 1) ptr[n] = incl[i] + bsums[blockIdx.x];
  }
}

__global__ void fill_kernel(const int* __restrict__ nidx, const int* __restrict__ hidx,
                            int* __restrict__ node_fill, int* __restrict__ he_fill,
                            int* __restrict__ node_hes, int* __restrict__ he_nodes) {
  int i = blockIdx.x * blockDim.x + threadIdx.x;
  if (i < N_INC) {
    int nn = nidx[i], hh = hidx[i];
    int p1 = atomicAdd(&node_fill[nn], 1);
    node_hes[p1] = hh;
    int p2 = atomicAdd(&he_fill[hh], 1);
    he_nodes[p2] = nn;
  }
}

// ---------------------------------------------------------------- converters / weight fold

__global__ void convert_x(const float* __restrict__ x, unsigned short* __restrict__ xb) {
  int i = blockIdx.x * 256 + threadIdx.x;      // 8 elems per thread
  if (i >= N_NODES * 16) return;
  const float4* p = (const float4*)x + (size_t)i * 2;
  float4 a = p[0], b = p[1];
  uint4 o;
  o.x = pack2(a.x, a.y); o.y = pack2(a.z, a.w);
  o.z = pack2(b.x, b.y); o.w = pack2(b.z, b.w);
  *(uint4*)(xb + (size_t)i * 8) = o;
}

// Fused BN-finalize + weight fold. gsum==nullptr -> identity (layer 1).
__global__ __launch_bounds__(256) void fold_w(
    const float* __restrict__ W, const float* __restrict__ gsum,
    const float* __restrict__ gss, const float* __restrict__ g,
    const float* __restrict__ be, unsigned short* __restrict__ WT,
    float* __restrict__ cvec, int K, int N, float invN) {
  int n = blockIdx.y * 256 + threadIdx.x;
  if (n >= N) return;
  int k0 = blockIdx.x * 16;
  float c = 0.f;
  unsigned short loc[16];
#pragma unroll
  for (int i = 0; i < 16; i++) {
    int k = k0 + i;
    float w = W[(size_t)k * N + n];
    float s = 1.f, t = 0.f;
    if (gsum) {
      float m = gsum[k] * invN;
      float v = gss[k] * invN - m * m;
      s = g[k] * rsqrtf(v + 1e-5f);
      t = be[k] - m * s;
    }
    loc[i] = f2bf(w * s);
    c += t * w;
  }
  *(uint4*)(WT + (size_t)n * K + k0)     = *(const uint4*)&loc[0];
  *(uint4*)(WT + (size_t)n * K + k0 + 8) = *(const uint4*)&loc[8];
  atomicAdd(cvec + n, c);
}

// ---------------------------------------------------------------- bf16 MFMA GEMM (m97 pattern)

__global__ __launch_bounds__(256) void gemm_mfma(
    const unsigned short* __restrict__ A, const unsigned short* __restrict__ BT,
    unsigned short* __restrict__ C, int K, int N) {
  __shared__ unsigned short As[128 * 32];
  __shared__ unsigned short Bs[128 * 32];
  const int tid  = threadIdx.x;
  const int w    = tid >> 6, lane = tid & 63;
  const int wm   = w & 1,  wn   = w >> 1;
  const int bm   = blockIdx.x * 128, bn = blockIdx.y * 128;
  const int quad = lane >> 4, r16 = lane & 15;

  floatx4 acc[4][4] = {};

  const int srow = (lane >> 2);
  const int scol = (lane & 3) * 8;

  for (int kb = 0; kb < K; kb += 32) {
#pragma unroll
    for (int i = 0; i < 2; i++) {
      const int row = (w * 2 + i) * 16 + srow;
      const unsigned short* ga = A  + (size_t)(bm + row) * K + kb + scol;
      const unsigned short* gb = BT + (size_t)(bn + row) * K + kb + scol;
      __builtin_amdgcn_global_load_lds(
          (const __attribute__((address_space(1))) void*)ga,
          (__attribute__((address_space(3))) void*)(&As[(w * 2 + i) * 512]), 16, 0, 0);
      __builtin_amdgcn_global_load_lds(
          (const __attribute__((address_space(1))) void*)gb,
          (__attribute__((address_space(3))) void*)(&Bs[(w * 2 + i) * 512]), 16, 0, 0);
    }
    __syncthreads();
    short8 af[4], bfr[4];
#pragma unroll
    for (int t = 0; t < 4; t++) {
      af[t]  = *(const short8*)&As[(wm * 64 + t * 16 + r16) * 32 + quad * 8];
      bfr[t] = *(const short8*)&Bs[(wn * 64 + t * 16 + r16) * 32 + quad * 8];
    }
#pragma unroll
    for (int mi = 0; mi < 4; mi++)
#pragma unroll
      for (int ni = 0; ni < 4; ni++)
        acc[mi][ni] = __builtin_amdgcn_mfma_f32_16x16x32_bf16(af[mi], bfr[ni], acc[mi][ni], 0, 0, 0);
    __syncthreads();
  }
#pragma unroll
  for (int mi = 0; mi < 4; mi++)
#pragma unroll
    for (int ni = 0; ni < 4; ni++)
#pragma unroll
      for (int rr = 0; rr < 4; rr++) {
        int gm = bm + wm * 64 + mi * 16 + quad * 4 + rr;
        int gn = bn + wn * 64 + ni * 16 + r16;
        C[(size_t)gm * N + gn] = f2bf(acc[mi][ni][rr]);
      }
}

// ---------------------------------------------------------------- aggregations (bf16 in/out)

// node -> hyperedge mean (deg~10). F/8 lanes per segment; shift=log2(F/8).
__global__ __launch_bounds__(256) void agg_he(
    const unsigned short* __restrict__ src, const int* __restrict__ ptr,
    const int* __restrict__ idx, unsigned short* __restrict__ dst,
    int F, int shift, int nSeg) {
  int seg = blockIdx.x * (256 >> shift) + (threadIdx.x >> shift);
  if (seg >= nSeg) return;
  int l = threadIdx.x & ((1 << shift) - 1);
  int c0 = l * 8;
  int beg = ptr[seg], end = ptr[seg + 1];
  float a[8] = {};
  gather8p(src, idx, beg, end, F, c0, a);
  float inv = (end > beg) ? 1.0f / (float)(end - beg) : 0.0f;
  uint4 o;
  o.x = pack2(a[0] * inv, a[1] * inv);
  o.y = pack2(a[2] * inv, a[3] * inv);
  o.z = pack2(a[4] * inv, a[5] * inv);
  o.w = pack2(a[6] * inv, a[7] * inv);
  *(uint4*)(dst + (size_t)seg * F + c0) = o;
}

// hyperedge -> node, F=256 (deg~3): PAIR-pipelined gather + bias(+cvec) + relu + BN stats.
// 64 nodes/block: 8 groups of 32 lanes; each group walks its 8 nodes in pairs —
// 4 clamped rows for node A + 4 for node B in flight together, next pair's idx
// prefetched while both are pending. deg>4 tails loop serially (rare).
__global__ __launch_bounds__(256) void node_agg_bn(
    const unsigned short* __restrict__ he, const int* __restrict__ nptr,
    const int* __restrict__ nhes, const float* __restrict__ b,
    const float* __restrict__ cvec, unsigned short* __restrict__ dst,
    float* __restrict__ gsum, float* __restrict__ gss) {
  const int F = 256;
  const int grp = threadIdx.x >> 5, l = threadIdx.x & 31, c0 = l * 8;
  float bb[8], cc[8];
#pragma unroll
  for (int j = 0; j < 8; j++) { bb[j] = b[c0 + j]; cc[j] = cvec[c0 + j]; }
  int begs[8], ends[8];
#pragma unroll
  for (int i = 0; i < 8; i++) {
    int n = blockIdx.x * 64 + i * 8 + grp;
    begs[i] = (n < N_NODES) ? nptr[n] : 0;
    ends[i] = (n < N_NODES) ? nptr[n + 1] : 0;
  }
  float s[8] = {}, ss[8] = {};
  int eA[4], eB[4];
#pragma unroll
  for (int k = 0; k < 4; k++) {
    eA[k] = (begs[0] < ends[0]) ? nhes[min(begs[0] + k, ends[0] - 1)] : 0;
    eB[k] = (begs[1] < ends[1]) ? nhes[min(begs[1] + k, ends[1] - 1)] : 0;
  }
  for (int p = 0; p < 8; p += 2) {
    const int begA = begs[p],     endA = ends[p],     dA = endA - begA;
    const int begB = begs[p + 1], endB = ends[p + 1], dB = endB - begB;
    R4 rA, rB;
    load4(he, eA, F, c0, rA);     // 8 row loads in flight
    load4(he, eB, F, c0, rB);
    if (p < 6) {                  // prefetch next pair's idx behind the row loads
      int b2 = begs[p + 2], e2 = ends[p + 2];
      int b3 = begs[p + 3], e3 = ends[p + 3];
#pragma unroll
      for (int k = 0; k < 4; k++) {
        eA[k] = (b2 < e2) ? nhes[min(b2 + k, e2 - 1)] : 0;
        eB[k] = (b3 < e3) ? nhes[min(b3 + k, e3 - 1)] : 0;
      }
    }
    float aA[8] = {}, aB[8] = {};
    accm4(rA, dA, aA);
    for (int j = begA + 4; j < endA; j += 4) {    // tail deg>4
      int et[4];
#pragma unroll
      for (int k = 0; k < 4; k++) et[k] = nhes[min(j + k, endA - 1)];
      R4 t; load4(he, et, F, c0, t);
      accm4(t, endA - j, aA);
    }
    accm4(rB, dB, aB);
    for (int j = begB + 4; j < endB; j += 4) {
      int et[4];
#pragma unroll
      for (int k = 0; k < 4; k++) et[k] = nhes[min(j + k, endB - 1)];
      R4 t; load4(he, et, F, c0, t);
      accm4(t, endB - j, aB);
    }
#pragma unroll
    for (int q = 0; q < 2; q++) {
      const int n = blockIdx.x * 64 + (p + q) * 8 + grp;
      if (n >= N_NODES) continue;
      const int d = q ? dB : dA;
      const float* a = q ? aB : aA;
      float inv  = (d > 0) ? 1.0f / (float)d : 0.0f;
      float cmul = (d > 0) ? 1.0f : 0.0f;      // deg-0 node: +b only
      float o[8];
#pragma unroll
      for (int j = 0; j < 8; j++) {
        o[j] = fmaxf(fmaf(a[j], inv, bb[j] + cmul * cc[j]), 0.f);
        s[j] += o[j]; ss[j] += o[j] * o[j];
      }
      uint4 ov;
      ov.x = pack2(o[0], o[1]); ov.y = pack2(o[2], o[3]);
      ov.z = pack2(o[4], o[5]); ov.w = pack2(o[6], o[7]);
      *(uint4*)(dst + (size_t)n * F + c0) = ov;
    }
  }
  __shared__ float Ls[8][256];
  __shared__ float Lss[8][256];
#pragma unroll
  for (int j = 0; j < 8; j++) { Ls[grp][c0 + j] = s[j]; Lss[grp][c0 + j] = ss[j]; }
  __syncthreads();
  int c = threadIdx.x;
  float a1 = 0.f, a2 = 0.f;
#pragma unroll
  for (int h = 0; h < 8; h++) { a1 += Ls[h][c]; a2 += Lss[h][c]; }
  atomicAdd(gsum + c, a1);
  atomicAdd(gss + c, a2);
}

// final hyperedge -> node, F=128, pair-pipelined, +b3(+c3 if deg>0), relu, f32 out.
// 32 nodes/block: 16 groups of 16 lanes, each group handles nodes (g, g+16).
__global__ __launch_bounds__(256) void agg_out(
    const unsigned short* __restrict__ he, const int* __restrict__ nptr,
    const int* __restrict__ nhes, const float* __restrict__ b,
    const float* __restrict__ cvec, float* __restrict__ out) {
  const int F = 128;
  int g = threadIdx.x >> 4, l = threadIdx.x & 15, c0 = l * 8;
  int nA = blockIdx.x * 32 + g, nB = nA + 16;
  int begA = (nA < N_NODES) ? nptr[nA] : 0;
  int endA = (nA < N_NODES) ? nptr[nA + 1] : 0;
  int begB = (nB < N_NODES) ? nptr[nB] : 0;
  int endB = (nB < N_NODES) ? nptr[nB + 1] : 0;
  int dA = endA - begA, dB = endB - begB;
  int eA[4], eB[4];
#pragma unroll
  for (int k = 0; k < 4; k++) {
    eA[k] = (dA > 0) ? nhes[min(begA + k, endA - 1)] : 0;
    eB[k] = (dB > 0) ? nhes[min(begB + k, endB - 1)] : 0;
  }
  R4 rA, rB;
  load4(he, eA, F, c0, rA);
  load4(he, eB, F, c0, rB);
  float aA[8] = {}, aB[8] = {};
  accm4(rA, dA, aA);
  for (int j = begA + 4; j < endA; j += 4) {
    int et[4];
#pragma unroll
    for (int k = 0; k < 4; k++) et[k] = nhes[min(j + k, endA - 1)];
    R4 t; load4(he, et, F, c0, t);
    accm4(t, endA - j, aA);
  }
  accm4(rB, dB, aB);
  for (int j = begB + 4; j < endB; j += 4) {
    int et[4];
#pragma unroll
    for (int k = 0; k < 4; k++) et[k] = nhes[min(j + k, endB - 1)];
    R4 t; load4(he, et, F, c0, t);
    accm4(t, endB - j, aB);
  }
#pragma unroll
  for (int q = 0; q < 2; q++) {
    int n = q ? nB : nA;
    if (n >= N_NODES) continue;
    int d = q ? dB : dA;
    const float* a = q ? aB : aA;
    float inv  = (d > 0) ? 1.0f / (float)d : 0.0f;
    float cmul = (d > 0) ? 1.0f : 0.0f;
    float4 o0, o1;
    o0.x = fmaxf(fmaf(a[0], inv, b[c0 + 0] + cmul * cvec[c0 + 0]), 0.f);
    o0.y = fmaxf(fmaf(a[1], inv, b[c0 + 1] + cmul * cvec[c0 + 1]), 0.f);
    o0.z = fmaxf(fmaf(a[2], inv, b[c0 + 2] + cmul * cvec[c0 + 2]), 0.f);
    o0.w = fmaxf(fmaf(a[3], inv, b[c0 + 3] + cmul * cvec[c0 + 3]), 0.f);
    o1.x = fmaxf(fmaf(a[4], inv, b[c0 + 4] + cmul * cvec[c0 + 4]), 0.f);
    o1.y = fmaxf(fmaf(a[5], inv, b[c0 + 5] + cmul * cvec[c0 + 5]), 0.f);
    o1.z = fmaxf(fmaf(a[6], inv, b[c0 + 6] + cmul * cvec[c0 + 6]), 0.f);
    o1.w = fmaxf(fmaf(a[7], inv, b[c0 + 7] + cmul * cvec[c0 + 7]), 0.f);
    float* dp = out + (size_t)n * F + c0;
    *(float4*)dp = o0;
    *(float4*)(dp + 4) = o1;
  }
}

// ---------------------------------------------------------------- launch

extern "C" void kernel_launch(void* const* d_in, const int* in_sizes, int n_in,
                              void* d_out, int out_size, void* d_ws, size_t ws_size,
                              hipStream_t stream) {
  const float* x    = (const float*)d_in[0];
  const int*   edge = (const int*)d_in[1];
  const int*   nidx = edge;
  const int*   hidx = edge + N_INC;
  const float* W1  = (const float*)d_in[2];
  const float* b1  = (const float*)d_in[3];
  const float* g1  = (const float*)d_in[4];
  const float* be1 = (const float*)d_in[5];
  const float* W2  = (const float*)d_in[6];
  const float* b2  = (const float*)d_in[7];
  const float* g2  = (const float*)d_in[8];
  const float* be2 = (const float*)d_in[9];
  const float* W3  = (const float*)d_in[10];
  const float* b3  = (const float*)d_in[11];
  float* out = (float*)d_out;

  char* ws = (char*)d_ws;
  size_t off = 0;
  auto alloc = [&](size_t bytes) -> void* {
    void* p = ws + off;
    off = (off + bytes + 255) & ~(size_t)255;
    return p;
  };
  unsigned short* Xb   = (unsigned short*)alloc((size_t)N_NODES * 128 * 2);
  unsigned short* Bb   = (unsigned short*)alloc((size_t)N_NODES * 256 * 2);
  unsigned short* Hraw = (unsigned short*)alloc((size_t)HEPAD * 256 * 2);
  unsigned short* HEb  = (unsigned short*)alloc((size_t)HEPAD * 256 * 2);
  unsigned short* W1T  = (unsigned short*)alloc((size_t)256 * 128 * 2);
  unsigned short* W2T  = (unsigned short*)alloc((size_t)256 * 256 * 2);
  unsigned short* W3T  = (unsigned short*)alloc((size_t)128 * 256 * 2);
  size_t zero_begin = off;
  int* he_cnt   = (int*)alloc((size_t)N_HE * 4);
  int* node_cnt = (int*)alloc((size_t)N_NODES * 4);
  float* gsum1 = (float*)alloc(1024);
  float* gss1  = (float*)alloc(1024);
  float* gsum2 = (float*)alloc(1024);
  float* gss2  = (float*)alloc(1024);
  float* c1 = (float*)alloc(1024);
  float* c2 = (float*)alloc(1024);
  float* c3 = (float*)alloc(1024);
  size_t zero_end = off;
  int* he_ptr    = (int*)alloc((size_t)(N_HE + 1) * 4);
  int* node_ptr  = (int*)alloc((size_t)(N_NODES + 1) * 4);
  int* he_fill   = (int*)alloc((size_t)N_HE * 4);
  int* node_fill = (int*)alloc((size_t)N_NODES * 4);
  int* he_nodes  = (int*)alloc((size_t)N_INC * 4);
  int* node_hes  = (int*)alloc((size_t)N_INC * 4);
  int* incl      = (int*)alloc((size_t)N_NODES * 4);
  int* bsums     = (int*)alloc(512);

  // ---- zero counters/accumulators (single async memset) ----
  hipMemsetAsync((void*)(ws + zero_begin), 0, zero_end - zero_begin, stream);

  // ---- CSR build ----
  count_kernel<<<(N_INC + 255) / 256, 256, 0, stream>>>(nidx, hidx, node_cnt, he_cnt);
  {
    int nb = (N_HE + 1023) / 1024;
    scan1<<<nb, 1024, 0, stream>>>(he_cnt, incl, bsums, N_HE);
    scan2<<<1, 64, 0, stream>>>(bsums, nb);
    scan3<<<nb, 1024, 0, stream>>>(he_cnt, incl, bsums, he_ptr, he_fill, N_HE);
  }
  {
    int nb = (N_NODES + 1023) / 1024;
    scan1<<<nb, 1024, 0, stream>>>(node_cnt, incl, bsums, N_NODES);
    scan2<<<1, 64, 0, stream>>>(bsums, nb);
    scan3<<<nb, 1024, 0, stream>>>(node_cnt, incl, bsums, node_ptr, node_fill, N_NODES);
  }
  fill_kernel<<<(N_INC + 255) / 256, 256, 0, stream>>>(nidx, hidx, node_fill, he_fill,
                                                       node_hes, he_nodes);

  // ---- precompute ----
  convert_x<<<(N_NODES * 16 + 255) / 256, 256, 0, stream>>>(x, Xb);
  { dim3 g(128 / 16, 1);
    fold_w<<<g, 256, 0, stream>>>(W1, nullptr, nullptr, nullptr, nullptr, W1T, c1, 128, 256, 0.f); }

  const int MBHE = HEPAD / 128;         // 235
  const float invN = 1.0f / (float)N_NODES;

  // ---- layer 1 ----
  agg_he<<<(N_HE + 15) / 16, 256, 0, stream>>>(Xb, he_ptr, he_nodes, Hraw, 128, 4, N_HE);
  { dim3 g(MBHE, 2); gemm_mfma<<<g, 256, 0, stream>>>(Hraw, W1T, HEb, 128, 256); }
  node_agg_bn<<<(N_NODES + 63) / 64, 256, 0, stream>>>(HEb, node_ptr, node_hes, b1, c1,
                                                       Bb, gsum1, gss1);

  // ---- layer 2 ----
  { dim3 g(256 / 16, 1);
    fold_w<<<g, 256, 0, stream>>>(W2, gsum1, gss1, g1, be1, W2T, c2, 256, 256, invN); }
  agg_he<<<(N_HE + 7) / 8, 256, 0, stream>>>(Bb, he_ptr, he_nodes, Hraw, 256, 5, N_HE);
  { dim3 g(MBHE, 2); gemm_mfma<<<g, 256, 0, stream>>>(Hraw, W2T, HEb, 256, 256); }
  node_agg_bn<<<(N_NODES + 63) / 64, 256, 0, stream>>>(HEb, node_ptr, node_hes, b2, c2,
                                                       Bb, gsum2, gss2);

  // ---- layer 3 ----
  { dim3 g(256 / 16, 1);
    fold_w<<<g, 256, 0, stream>>>(W3, gsum2, gss2, g2, be2, W3T, c3, 256, 128, invN); }
  agg_he<<<(N_HE + 7) / 8, 256, 0, stream>>>(Bb, he_ptr, he_nodes, Hraw, 256, 5, N_HE);
  { dim3 g(MBHE, 1); gemm_mfma<<<g, 256, 0, stream>>>(Hraw, W3T, HEb, 256, 128); }
  agg_out<<<(N_NODES + 31) / 32, 256, 0, stream>>>(HEb, node_ptr, node_hes, b3, c3, out);
}